// Round 5
// baseline (534.112 us; speedup 1.0000x reference)
//
#include <hip/hip_runtime.h>
#include <hip/hip_cooperative_groups.h>

namespace cg = cooperative_groups;

#define BB 16
#define NN 512
#define NI 32
#define NHEAD 8
#define NH 512
#define NO 64
#define ROWS (BB*NN)   // 8192
#define EPSV 1e-5f
#define SLOPE 0.05f
#define GRID_BLKS 512
#define BLK_THR 256

typedef __attribute__((ext_vector_type(4))) float f32x4;
typedef __attribute__((ext_vector_type(8))) short s16x8;

static __device__ __forceinline__ ushort f2bf(float f) {
    union { float f; unsigned u; } v; v.f = f;
    unsigned r = v.u + 0x7fff + ((v.u >> 16) & 1);   // RNE
    return (ushort)(r >> 16);
}

static __device__ __forceinline__ unsigned cvt_pk_bf16(float lo, float hi) {
    unsigned r;
    asm("v_cvt_pk_bf16_f32 %0, %1, %2" : "=v"(r) : "v"(lo), "v"(hi));
    return r;
}

#define GLOAD_LDS16(g, l) __builtin_amdgcn_global_load_lds( \
    (const __attribute__((address_space(1))) void*)(g),     \
    (__attribute__((address_space(3))) void*)(l), 16, 0, 0)

// LDS union across phases (max 40960 B -> 2 blocks/CU needs 80KB <= 160KB).
struct GetvS { ushort xT[32 * 512]; float poss[NN * 4]; };                  // 40960 B
struct GemmS { ushort As[2][4096]; ushort Bs[2][2048]; float red[2][64]; }; // 25088 B
struct G3S   { ushort As3[2][512]; ushort Bs3[2][2048]; float red3[2][64]; };
union SMemU { GetvS g; GemmS mm; G3S m3; };

// getv x^T tile swizzle: spreads 8 i-rows across the 8 16B-chunks of a 128B span.
#define XTI(i, m) ((((i) * 512) + (m)) ^ (((i) & 7) << 3))

// ---------------------------------------------------------------------------
// gemm phase, BM=128 (FM=2), BK=32, 4 waves. 2-phase double buffer.
// LDS tiles XOR-swizzled both-sides: source chunk = (t&3)^(srow&3), read
// offset lk ^ ((la&3)<<3)  -> quarter-wave ds_read_b128 spreads over all banks.
// ---------------------------------------------------------------------------
template <int K, int NC>
static __device__ void gemm_phase(SMemU& sm, const ushort* __restrict__ A,
                                  const ushort* __restrict__ W,
                                  const float* __restrict__ bias,
                                  float* __restrict__ C,
                                  float* __restrict__ sums, float* __restrict__ sumsq,
                                  int m0, int n0, int t) {
    constexpr int KS = K / 32;
    const int lane = t & 63;
    const int w = t >> 6;
    const int la = lane & 15;
    const int lk = (lane >> 4) * 8;
    const int lks = lk ^ ((la & 3) << 3);
    const int srow = t >> 2;
    const int scol = ((t & 3) ^ (srow & 3)) * 8;

    auto& As = sm.mm.As; auto& Bs = sm.mm.Bs; auto& red = sm.mm.red;
    if (t < 64) { red[0][t] = 0.f; red[1][t] = 0.f; }

    f32x4 acc[2][4];
#pragma unroll
    for (int fm = 0; fm < 2; ++fm)
#pragma unroll
        for (int fn = 0; fn < 4; ++fn) acc[fm][fn] = (f32x4){0.f, 0.f, 0.f, 0.f};

    auto STAGE = [&](int buf, int k0) {
        GLOAD_LDS16(A + (size_t)(m0 + srow) * K + k0 + scol, &As[buf][t * 8]);
        GLOAD_LDS16(A + (size_t)(m0 + 64 + srow) * K + k0 + scol, &As[buf][2048 + t * 8]);
        GLOAD_LDS16(W + (size_t)(n0 + srow) * K + k0 + scol, &Bs[buf][t * 8]);
    };

    STAGE(0, 0);
    __syncthreads();
    int cur = 0;
    for (int ks = 0; ks < KS; ++ks) {
        if (ks + 1 < KS) STAGE(cur ^ 1, (ks + 1) * 32);
        s16x8 b0 = *reinterpret_cast<const s16x8*>(&Bs[cur][(0 + la) * 32 + lks]);
        s16x8 b1 = *reinterpret_cast<const s16x8*>(&Bs[cur][(16 + la) * 32 + lks]);
        s16x8 b2 = *reinterpret_cast<const s16x8*>(&Bs[cur][(32 + la) * 32 + lks]);
        s16x8 b3 = *reinterpret_cast<const s16x8*>(&Bs[cur][(48 + la) * 32 + lks]);
#pragma unroll
        for (int fm = 0; fm < 2; ++fm) {
            s16x8 a = *reinterpret_cast<const s16x8*>(&As[cur][(w * 32 + fm * 16 + la) * 32 + lks]);
            acc[fm][0] = __builtin_amdgcn_mfma_f32_16x16x32_bf16(a, b0, acc[fm][0], 0, 0, 0);
            acc[fm][1] = __builtin_amdgcn_mfma_f32_16x16x32_bf16(a, b1, acc[fm][1], 0, 0, 0);
            acc[fm][2] = __builtin_amdgcn_mfma_f32_16x16x32_bf16(a, b2, acc[fm][2], 0, 0, 0);
            acc[fm][3] = __builtin_amdgcn_mfma_f32_16x16x32_bf16(a, b3, acc[fm][3], 0, 0, 0);
        }
        __syncthreads();
        cur ^= 1;
    }

    float bv[4], s[4] = {}, q[4] = {};
#pragma unroll
    for (int fn = 0; fn < 4; ++fn) bv[fn] = bias[n0 + fn * 16 + la];

#pragma unroll
    for (int fm = 0; fm < 2; ++fm)
#pragma unroll
        for (int fn = 0; fn < 4; ++fn)
#pragma unroll
            for (int r = 0; r < 4; ++r) {
                int row = m0 + w * 32 + fm * 16 + (lane >> 4) * 4 + r;
                float v = acc[fm][fn][r] + bv[fn];
                C[(size_t)row * NC + n0 + fn * 16 + la] = v;
                s[fn] += v; q[fn] += v * v;
            }
#pragma unroll
    for (int fn = 0; fn < 4; ++fn) {
        s[fn] += __shfl_xor(s[fn], 16); s[fn] += __shfl_xor(s[fn], 32);
        q[fn] += __shfl_xor(q[fn], 16); q[fn] += __shfl_xor(q[fn], 32);
    }
    if (lane < 16) {
#pragma unroll
        for (int fn = 0; fn < 4; ++fn) {
            atomicAdd(&red[0][fn * 16 + lane], s[fn]);
            atomicAdd(&red[1][fn * 16 + lane], q[fn]);
        }
    }
    __syncthreads();
    if (t < 64) {
        atomicAdd(&sums[n0 + t], red[0][t]);
        atomicAdd(&sumsq[n0 + t], red[1][t]);
    }
}

// ---------------------------------------------------------------------------
// BN apply + leaky ReLU -> bf16 (grid-stride over whole tensor).
// ---------------------------------------------------------------------------
static __device__ void bnact_phase(const float* __restrict__ Yin, ushort* __restrict__ Yout,
                                   const float* __restrict__ sums, const float* __restrict__ sumsq,
                                   const float* __restrict__ g, const float* __restrict__ bt,
                                   int gid) {
    const float invn = 1.f / (float)ROWS;
    for (int e = gid; e < ROWS * NH / 4; e += GRID_BLKS * BLK_THR) {
        int c0 = (e * 4) & (NH - 1);
        float4 v = reinterpret_cast<const float4*>(Yin)[e];
        float vv[4] = {v.x, v.y, v.z, v.w};
        ushort oo[4];
#pragma unroll
        for (int j = 0; j < 4; ++j) {
            int c = c0 + j;
            float m = sums[c] * invn;
            float var = sumsq[c] * invn - m * m;
            float rs = rsqrtf(var + EPSV);
            float val = (vv[j] - m) * rs * g[c] + bt[c];
            val = val > 0.f ? val : SLOPE * val;
            oo[j] = f2bf(val);
        }
        *reinterpret_cast<ushort4*>(Yout + (size_t)e * 4) = make_ushort4(oo[0], oo[1], oo[2], oo[3]);
    }
}

// ---------------------------------------------------------------------------
// The mega-kernel: 7 phases separated by grid.sync().
// ---------------------------------------------------------------------------
__global__ __launch_bounds__(BLK_THR, 2) void mega(
    const float* __restrict__ x, const float* __restrict__ Qm,
    const float* __restrict__ W1, const float* __restrict__ b1,
    const float* __restrict__ g1, const float* __restrict__ bt1,
    const float* __restrict__ W2, const float* __restrict__ b2,
    const float* __restrict__ g2, const float* __restrict__ bt2,
    const float* __restrict__ W3, const float* __restrict__ b3,
    const float* __restrict__ g3, const float* __restrict__ bt3,
    float* __restrict__ out, char* __restrict__ wsb) {
    __shared__ SMemU sm;
    cg::grid_group grid = cg::this_grid();

    // ws layout (sequenced aliasing is safe across phase boundaries):
    float*  Yf  = (float*)wsb;                       // [0,16M) fp32 8192x512
    ushort* Vb  = (ushort*)(wsb + (16u << 20));      // [16,20M) bf16 8192x256 (dead after gemm1)
    ushort* Y1b = (ushort*)(wsb + (20u << 20));      // [20,28M) (dead after gemm2)
    ushort* Y2b = (ushort*)(wsb + (16u << 20));      // [16,24M) overwrites Vb+Y1b-lo after both dead
    ushort* W1b = (ushort*)(wsb + (28u << 20));
    ushort* W2b = W1b + 512 * 256;
    ushort* W3b = W2b + 512 * 512;
    float*  st  = (float*)(W3b + 64 * 512);
    float* s1 = st;        float* q1 = s1 + 512;
    float* s2 = q1 + 512;  float* q2 = s2 + 512;
    float* s3 = q2 + 512;  float* q3 = s3 + 64;

    const int t = threadIdx.x;
    const int blk = blockIdx.x;
    const int lane = t & 63;
    const int w = t >> 6;
    const int gid = blk * BLK_THR + t;

    // ---- phase 0: zero stats + weight conv + getv ----
    if (gid < 2176) st[gid] = 0.f;
    if (gid < 32768) {
        float4 v = reinterpret_cast<const float4*>(W1)[gid];
        *reinterpret_cast<ushort4*>(W1b + (size_t)gid * 4) =
            make_ushort4(f2bf(v.x), f2bf(v.y), f2bf(v.z), f2bf(v.w));
    }
    if (gid < 65536) {
        float4 v = reinterpret_cast<const float4*>(W2)[gid];
        *reinterpret_cast<ushort4*>(W2b + (size_t)gid * 4) =
            make_ushort4(f2bf(v.x), f2bf(v.y), f2bf(v.z), f2bf(v.w));
    }
    if (gid < 8192) {
        float4 v = reinterpret_cast<const float4*>(W3)[gid];
        *reinterpret_cast<ushort4*>(W3b + (size_t)gid * 4) =
            make_ushort4(f2bf(v.x), f2bf(v.y), f2bf(v.z), f2bf(v.w));
    }

    {   // getv: 32 blocks per b; each block stages x[b] once, does 2 (h,n-chunk) tiles
        const int b = blk >> 5;
        const float4* xg = reinterpret_cast<const float4*>(x + (size_t)b * NN * NI);
#pragma unroll
        for (int j = 0; j < 16; ++j) {
            int e = t + j * 256;              // float4 index 0..4095
            int m = e >> 3, i4 = e & 7;
            float4 v = xg[e];
            unsigned p01 = cvt_pk_bf16(v.x, v.y);
            unsigned p23 = cvt_pk_bf16(v.z, v.w);
            sm.g.xT[XTI(i4 * 4 + 0, m)] = (ushort)(p01 & 0xffff);
            sm.g.xT[XTI(i4 * 4 + 1, m)] = (ushort)(p01 >> 16);
            sm.g.xT[XTI(i4 * 4 + 2, m)] = (ushort)(p23 & 0xffff);
            sm.g.xT[XTI(i4 * 4 + 3, m)] = (ushort)(p23 >> 16);
            if (i4 == 0) *reinterpret_cast<float4*>(&sm.g.poss[m * 4]) = v;
        }
        __syncthreads();

        const int la = lane & 15;
        const int mko = (lane >> 4) * 8;
#pragma unroll 1
        for (int rep = 0; rep < 2; ++rep) {
            const int tile = (blk & 31) * 2 + rep;   // 0..63
            const int h = tile >> 3;
            const int nb = (tile & 7) * 64;
            const float qx = Qm[h * 3 + 0], qy = Qm[h * 3 + 1], qz = Qm[h * 3 + 2];
            const int n_a = nb + w * 16 + la;
            float4 pa = *reinterpret_cast<const float4*>(&sm.g.poss[n_a * 4]);
            const float c0 = pa.x - qx, c1 = pa.y - qy, c2 = pa.z - qz;

            f32x4 acc0 = {0.f, 0.f, 0.f, 0.f}, acc1 = {0.f, 0.f, 0.f, 0.f};
            for (int mc = 0; mc < NN; mc += 32) {
                float d[8];
#pragma unroll
                for (int j = 0; j < 8; ++j) {
                    float4 pm = *reinterpret_cast<const float4*>(&sm.g.poss[(mc + mko + j) * 4]);
                    float t0 = c0 - pm.x, t1 = c1 - pm.y, t2 = c2 - pm.z;
                    float e = fmaf(t0, t0, fmaf(t1, t1, t2 * t2));
                    d[j] = exp2f(e * -1.4426950408889634f);
                }
                union { s16x8 v; unsigned u[4]; } af;
#pragma unroll
                for (int j = 0; j < 4; ++j) af.u[j] = cvt_pk_bf16(d[2 * j], d[2 * j + 1]);
                s16x8 bb0 = *reinterpret_cast<const s16x8*>(&sm.g.xT[XTI(la, mc + mko)]);
                s16x8 bb1 = *reinterpret_cast<const s16x8*>(&sm.g.xT[XTI(la + 16, mc + mko)]);
                acc0 = __builtin_amdgcn_mfma_f32_16x16x32_bf16(af.v, bb0, acc0, 0, 0, 0);
                acc1 = __builtin_amdgcn_mfma_f32_16x16x32_bf16(af.v, bb1, acc1, 0, 0, 0);
            }
            const int i = la;
#pragma unroll
            for (int r = 0; r < 4; ++r) {
                int n = nb + w * 16 + (lane >> 4) * 4 + r;
                float v0 = acc0[r], v1 = acc1[r];
                if (i < 3) {
                    const float* p = &sm.g.poss[n * 4];
                    v0 -= (i == 0) ? p[0] : (i == 1) ? p[1] : p[2];
                }
                ushort* vp = Vb + (((size_t)(b * NN + n)) * NHEAD + h) * NI;
                vp[i] = f2bf(v0);
                vp[i + 16] = f2bf(v1);
            }
        }
    }
    grid.sync();

    // ---- phase 1: gemm1 (K=256, NC=512) ----
    gemm_phase<256, 512>(sm, Vb, W1b, b1, Yf, s1, q1, (blk >> 3) * 128, (blk & 7) * 64, t);
    grid.sync();

    // ---- phase 2: bnact1 -> Y1b ----
    bnact_phase(Yf, Y1b, s1, q1, g1, bt1, gid);
    grid.sync();

    // ---- phase 3: gemm2 (K=512, NC=512) ----
    gemm_phase<512, 512>(sm, Y1b, W2b, b2, Yf, s2, q2, (blk >> 3) * 128, (blk & 7) * 64, t);
    grid.sync();

    // ---- phase 4: bnact2 -> Y2b ----
    bnact_phase(Yf, Y2b, s2, q2, g2, bt2, gid);
    grid.sync();

    // ---- phase 5: gemm3 (K=512, NC=64, BM=16; 512 tasks -> all CUs) ----
    {
        const int m0 = blk * 16;
        const int la = lane & 15;
        const int lk = (lane >> 4) * 8;
        const int lks = lk ^ ((la & 3) << 3);
        const int srow = lane >> 2;
        const int scol = ((lane & 3) ^ (srow & 3)) * 8;
        auto& As3 = sm.m3.As3; auto& Bs3 = sm.m3.Bs3;

        f32x4 acc = {0.f, 0.f, 0.f, 0.f};
        auto STAGE3 = [&](int buf, int k0) {
            if (w == 0)
                GLOAD_LDS16(Y2b + (size_t)(m0 + srow) * 512 + k0 + scol, &As3[buf][lane * 8]);
            GLOAD_LDS16(W3b + (size_t)(w * 16 + srow) * 512 + k0 + scol, &Bs3[buf][t * 8]);
        };
        STAGE3(0, 0);
        __syncthreads();
        int cur = 0;
        for (int ks = 0; ks < 16; ++ks) {
            if (ks + 1 < 16) STAGE3(cur ^ 1, (ks + 1) * 32);
            s16x8 a = *reinterpret_cast<const s16x8*>(&As3[cur][la * 32 + lks]);
            s16x8 bb = *reinterpret_cast<const s16x8*>(&Bs3[cur][(w * 16 + la) * 32 + lks]);
            acc = __builtin_amdgcn_mfma_f32_16x16x32_bf16(a, bb, acc, 0, 0, 0);
            __syncthreads();
            cur ^= 1;
        }
        float bv = b3[w * 16 + la];
        float s = 0.f, q = 0.f;
#pragma unroll
        for (int r = 0; r < 4; ++r) {
            int row = m0 + (lane >> 4) * 4 + r;
            float v = acc[r] + bv;
            Yf[(size_t)row * NO + w * 16 + la] = v;
            s += v; q += v * v;
        }
        s += __shfl_xor(s, 16); s += __shfl_xor(s, 32);
        q += __shfl_xor(q, 16); q += __shfl_xor(q, 32);
        if (lane < 16) {
            atomicAdd(&s3[w * 16 + la], s);
            atomicAdd(&q3[w * 16 + la], q);
        }
    }
    grid.sync();

    // ---- phase 6: final BN -> out (exactly one float4 per thread) ----
    {
        const float invn = 1.f / (float)ROWS;
        int e = gid;                       // 131072 float4 = ROWS*NO/4
        int c0 = (e * 4) & (NO - 1);
        float4 v = reinterpret_cast<const float4*>(Yf)[e];
        float vv[4] = {v.x, v.y, v.z, v.w};
        float oo[4];
#pragma unroll
        for (int j = 0; j < 4; ++j) {
            int c = c0 + j;
            float m = s3[c] * invn;
            float var = q3[c] * invn - m * m;
            float rs = rsqrtf(var + EPSV);
            oo[j] = (vv[j] - m) * rs * g3[c] + bt3[c];
        }
        reinterpret_cast<float4*>(out)[e] = make_float4(oo[0], oo[1], oo[2], oo[3]);
    }
}

extern "C" void kernel_launch(void* const* d_in, const int* in_sizes, int n_in,
                              void* d_out, int out_size, void* d_ws, size_t ws_size,
                              hipStream_t stream) {
    const float* x   = (const float*)d_in[0];
    const float* Q   = (const float*)d_in[1];
    const float* W1  = (const float*)d_in[2];
    const float* b1  = (const float*)d_in[3];
    const float* g1  = (const float*)d_in[4];
    const float* bt1 = (const float*)d_in[5];
    const float* W2  = (const float*)d_in[6];
    const float* b2  = (const float*)d_in[7];
    const float* g2  = (const float*)d_in[8];
    const float* bt2 = (const float*)d_in[9];
    const float* W3  = (const float*)d_in[10];
    const float* b3  = (const float*)d_in[11];
    const float* g3  = (const float*)d_in[12];
    const float* bt3 = (const float*)d_in[13];
    float* out = (float*)d_out;
    char* wsb = (char*)d_ws;

    void* args[] = {(void*)&x, (void*)&Q,
                    (void*)&W1, (void*)&b1, (void*)&g1, (void*)&bt1,
                    (void*)&W2, (void*)&b2, (void*)&g2, (void*)&bt2,
                    (void*)&W3, (void*)&b3, (void*)&g3, (void*)&bt3,
                    (void*)&out, (void*)&wsb};
    hipLaunchCooperativeKernel((const void*)mega, dim3(GRID_BLKS), dim3(BLK_THR),
                               args, 0, stream);
}

// Round 7
// 171.976 us; speedup vs baseline: 3.1057x; 3.1057x over previous
//
#include <hip/hip_runtime.h>

#define BB 16
#define NN 512
#define NI 32
#define NHEAD 8
#define NH 512
#define NO 64
#define ROWS (BB*NN)   // 8192
#define EPSV 1e-5f
#define SLOPE 0.05f

typedef __attribute__((ext_vector_type(4))) float f32x4;
typedef __attribute__((ext_vector_type(8))) short s16x8;

static __device__ __forceinline__ ushort f2bf(float f) {
    union { float f; unsigned u; } v; v.f = f;
    unsigned r = v.u + 0x7fff + ((v.u >> 16) & 1);   // RNE
    return (ushort)(r >> 16);
}

static __device__ __forceinline__ unsigned cvt_pk_bf16(float lo, float hi) {
    unsigned r;
    asm("v_cvt_pk_bf16_f32 %0, %1, %2" : "=v"(r) : "v"(lo), "v"(hi));
    return r;
}

#define GLOAD_LDS16(g, l) __builtin_amdgcn_global_load_lds( \
    (const __attribute__((address_space(1))) void*)(g),     \
    (__attribute__((address_space(3))) void*)(l), 16, 0, 0)

// getv x^T tile swizzle.
#define XTI(i, m) ((((i) * 512) + (m)) ^ (((i) & 7) << 3))

// ---------------------------------------------------------------------------
// Dispatch 1: blocks [0,1024) = getv (R3-verified MFMA version, 1 tile each);
// blocks [1024,1088) = weight bf16 conversion + stats zeroing.
// ---------------------------------------------------------------------------
__global__ __launch_bounds__(256) void k_getv_wconv(
    const float* __restrict__ x, const float* __restrict__ Qm,
    ushort* __restrict__ Vb,
    const float* __restrict__ W1, const float* __restrict__ W2,
    const float* __restrict__ W3,
    ushort* __restrict__ W1b, ushort* __restrict__ W2b, ushort* __restrict__ W3b,
    float* __restrict__ st) {
    const int blk = blockIdx.x;
    const int t = threadIdx.x;

    if (blk >= 1024) {   // wconv + stats-zero
        const int gid = (blk - 1024) * 256 + t;   // 0..16383
        if (gid < 2176) st[gid] = 0.f;
#pragma unroll
        for (int r = 0; r < 2; ++r) {
            int i = gid + r * 16384;
            if (i < 32768) {
                float4 v = reinterpret_cast<const float4*>(W1)[i];
                *reinterpret_cast<ushort4*>(W1b + (size_t)i * 4) =
                    make_ushort4(f2bf(v.x), f2bf(v.y), f2bf(v.z), f2bf(v.w));
            }
        }
#pragma unroll
        for (int r = 0; r < 4; ++r) {
            int i = gid + r * 16384;
            float4 v = reinterpret_cast<const float4*>(W2)[i];
            *reinterpret_cast<ushort4*>(W2b + (size_t)i * 4) =
                make_ushort4(f2bf(v.x), f2bf(v.y), f2bf(v.z), f2bf(v.w));
        }
        if (gid < 8192) {
            float4 v = reinterpret_cast<const float4*>(W3)[gid];
            *reinterpret_cast<ushort4*>(W3b + (size_t)gid * 4) =
                make_ushort4(f2bf(v.x), f2bf(v.y), f2bf(v.z), f2bf(v.w));
        }
        return;
    }

    __shared__ ushort xT[32 * 512];   // 32 KB, swizzled
    __shared__ float poss[NN * 4];    // 8 KB
    const int b = blk >> 6;
    const int tile = blk & 63;
    const int lane = t & 63;
    const int w = t >> 6;
    const int h = tile >> 3;
    const int nb = (tile & 7) * 64;

    const float4* xg = reinterpret_cast<const float4*>(x + (size_t)b * NN * NI);
#pragma unroll
    for (int j = 0; j < 16; ++j) {
        int e = t + j * 256;
        int m = e >> 3, i4 = e & 7;
        float4 v = xg[e];
        unsigned p01 = cvt_pk_bf16(v.x, v.y);
        unsigned p23 = cvt_pk_bf16(v.z, v.w);
        xT[XTI(i4 * 4 + 0, m)] = (ushort)(p01 & 0xffff);
        xT[XTI(i4 * 4 + 1, m)] = (ushort)(p01 >> 16);
        xT[XTI(i4 * 4 + 2, m)] = (ushort)(p23 & 0xffff);
        xT[XTI(i4 * 4 + 3, m)] = (ushort)(p23 >> 16);
        if (i4 == 0) *reinterpret_cast<float4*>(&poss[m * 4]) = v;
    }
    __syncthreads();

    const int la = lane & 15;
    const int mko = (lane >> 4) * 8;
    const float qx = Qm[h * 3 + 0], qy = Qm[h * 3 + 1], qz = Qm[h * 3 + 2];
    const int n_a = nb + w * 16 + la;
    float4 pa = *reinterpret_cast<const float4*>(&poss[n_a * 4]);
    const float c0 = pa.x - qx, c1 = pa.y - qy, c2 = pa.z - qz;

    f32x4 acc0 = {0.f, 0.f, 0.f, 0.f}, acc1 = {0.f, 0.f, 0.f, 0.f};
    for (int mc = 0; mc < NN; mc += 32) {
        float d[8];
#pragma unroll
        for (int j = 0; j < 8; ++j) {
            float4 pm = *reinterpret_cast<const float4*>(&poss[(mc + mko + j) * 4]);
            float t0 = c0 - pm.x, t1 = c1 - pm.y, t2 = c2 - pm.z;
            float e = fmaf(t0, t0, fmaf(t1, t1, t2 * t2));
            d[j] = exp2f(e * -1.4426950408889634f);
        }
        union { s16x8 v; unsigned u[4]; } af;
#pragma unroll
        for (int j = 0; j < 4; ++j) af.u[j] = cvt_pk_bf16(d[2 * j], d[2 * j + 1]);
        s16x8 bb0 = *reinterpret_cast<const s16x8*>(&xT[XTI(la, mc + mko)]);
        s16x8 bb1 = *reinterpret_cast<const s16x8*>(&xT[XTI(la + 16, mc + mko)]);
        acc0 = __builtin_amdgcn_mfma_f32_16x16x32_bf16(af.v, bb0, acc0, 0, 0, 0);
        acc1 = __builtin_amdgcn_mfma_f32_16x16x32_bf16(af.v, bb1, acc1, 0, 0, 0);
    }
    const int i = la;
#pragma unroll
    for (int r = 0; r < 4; ++r) {
        int n = nb + w * 16 + (lane >> 4) * 4 + r;
        float v0 = acc0[r], v1 = acc1[r];
        if (i < 3) {
            const float* p = &poss[n * 4];
            v0 -= (i == 0) ? p[0] : (i == 1) ? p[1] : p[2];
        }
        ushort* vp = Vb + (((size_t)(b * NN + n)) * NHEAD + h) * NI;
        vp[i] = f2bf(v0);
        vp[i + 16] = f2bf(v1);
    }
}

// ---------------------------------------------------------------------------
// Dispatch 2: gemm1 (A bf16 via global_load_lds), BM=128, fused stats.
// Same as R3's proven gemm_phase.
// ---------------------------------------------------------------------------
__global__ __launch_bounds__(256) void k_gemm1(const ushort* __restrict__ A,
                                               const ushort* __restrict__ W,
                                               const float* __restrict__ bias,
                                               float* __restrict__ C,
                                               float* __restrict__ sums,
                                               float* __restrict__ sumsq) {
    constexpr int K = 256, NC = 512, KS = K / 32;
    __shared__ ushort As[2][4096];
    __shared__ ushort Bs[2][2048];
    __shared__ float red[2][64];
    const int t = threadIdx.x;
    const int lane = t & 63;
    const int w = t >> 6;
    const int m0 = blockIdx.y * 128;
    const int n0 = blockIdx.x * 64;
    const int la = lane & 15;
    const int lk = (lane >> 4) * 8;
    const int lks = lk ^ ((la & 3) << 3);
    const int srow = t >> 2;
    const int scol = ((t & 3) ^ (srow & 3)) * 8;

    if (t < 64) { red[0][t] = 0.f; red[1][t] = 0.f; }

    f32x4 acc[2][4];
#pragma unroll
    for (int fm = 0; fm < 2; ++fm)
#pragma unroll
        for (int fn = 0; fn < 4; ++fn) acc[fm][fn] = (f32x4){0.f, 0.f, 0.f, 0.f};

    auto STAGE = [&](int buf, int k0) {
        GLOAD_LDS16(A + (size_t)(m0 + srow) * K + k0 + scol, &As[buf][t * 8]);
        GLOAD_LDS16(A + (size_t)(m0 + 64 + srow) * K + k0 + scol, &As[buf][2048 + t * 8]);
        GLOAD_LDS16(W + (size_t)(n0 + srow) * K + k0 + scol, &Bs[buf][t * 8]);
    };

    STAGE(0, 0);
    __syncthreads();
    int cur = 0;
    for (int ks = 0; ks < KS; ++ks) {
        if (ks + 1 < KS) STAGE(cur ^ 1, (ks + 1) * 32);
        s16x8 b0 = *reinterpret_cast<const s16x8*>(&Bs[cur][(0 + la) * 32 + lks]);
        s16x8 b1 = *reinterpret_cast<const s16x8*>(&Bs[cur][(16 + la) * 32 + lks]);
        s16x8 b2 = *reinterpret_cast<const s16x8*>(&Bs[cur][(32 + la) * 32 + lks]);
        s16x8 b3 = *reinterpret_cast<const s16x8*>(&Bs[cur][(48 + la) * 32 + lks]);
#pragma unroll
        for (int fm = 0; fm < 2; ++fm) {
            s16x8 a = *reinterpret_cast<const s16x8*>(&As[cur][(w * 32 + fm * 16 + la) * 32 + lks]);
            acc[fm][0] = __builtin_amdgcn_mfma_f32_16x16x32_bf16(a, b0, acc[fm][0], 0, 0, 0);
            acc[fm][1] = __builtin_amdgcn_mfma_f32_16x16x32_bf16(a, b1, acc[fm][1], 0, 0, 0);
            acc[fm][2] = __builtin_amdgcn_mfma_f32_16x16x32_bf16(a, b2, acc[fm][2], 0, 0, 0);
            acc[fm][3] = __builtin_amdgcn_mfma_f32_16x16x32_bf16(a, b3, acc[fm][3], 0, 0, 0);
        }
        __syncthreads();
        cur ^= 1;
    }

    float bv[4], s[4] = {}, q[4] = {};
#pragma unroll
    for (int fn = 0; fn < 4; ++fn) bv[fn] = bias[n0 + fn * 16 + la];
#pragma unroll
    for (int fm = 0; fm < 2; ++fm)
#pragma unroll
        for (int fn = 0; fn < 4; ++fn)
#pragma unroll
            for (int r = 0; r < 4; ++r) {
                int row = m0 + w * 32 + fm * 16 + (lane >> 4) * 4 + r;
                float v = acc[fm][fn][r] + bv[fn];
                C[(size_t)row * NC + n0 + fn * 16 + la] = v;
                s[fn] += v; q[fn] += v * v;
            }
#pragma unroll
    for (int fn = 0; fn < 4; ++fn) {
        s[fn] += __shfl_xor(s[fn], 16); s[fn] += __shfl_xor(s[fn], 32);
        q[fn] += __shfl_xor(q[fn], 16); q[fn] += __shfl_xor(q[fn], 32);
    }
    if (lane < 16) {
#pragma unroll
        for (int fn = 0; fn < 4; ++fn) {
            atomicAdd(&red[0][fn * 16 + lane], s[fn]);
            atomicAdd(&red[1][fn * 16 + lane], q[fn]);
        }
    }
    __syncthreads();
    if (t < 64) {
        atomicAdd(&sums[n0 + t], red[0][t]);
        atomicAdd(&sumsq[n0 + t], red[1][t]);
    }
}

// ---------------------------------------------------------------------------
// Dispatch 3: gemm with BN+leakyReLU of the PREVIOUS layer fused into the
// A-staging path. A = raw fp32 (pre-BN); per-column affine coeffs computed
// once per block. A-tile: regs->BN->bf16->swizzled ds_write (matches lks).
// ---------------------------------------------------------------------------
template <int K, int NC>
__global__ __launch_bounds__(256) void k_gemm_bn(const float* __restrict__ Araw,
                                                 const ushort* __restrict__ W,
                                                 const float* __restrict__ bias,
                                                 const float* __restrict__ psum,
                                                 const float* __restrict__ psumsq,
                                                 const float* __restrict__ pg,
                                                 const float* __restrict__ pbt,
                                                 float* __restrict__ C,
                                                 float* __restrict__ sums,
                                                 float* __restrict__ sumsq) {
    constexpr int KS = K / 32;
    __shared__ ushort As[2][4096];
    __shared__ ushort Bs[2][2048];
    __shared__ float ca[K], cd[K];
    __shared__ float red[2][64];
    const int t = threadIdx.x;
    const int lane = t & 63;
    const int w = t >> 6;
    const int m0 = blockIdx.y * 128;
    const int n0 = blockIdx.x * 64;
    const int la = lane & 15;
    const int lk = (lane >> 4) * 8;
    const int lks = lk ^ ((la & 3) << 3);
    const int srow = t >> 2;
    const int scol = ((t & 3) ^ (srow & 3)) * 8;
    const float invn = 1.f / (float)ROWS;

    // per-column BN coefficients of the previous layer
    for (int c = t; c < K; c += 256) {
        float m = psum[c] * invn;
        float var = psumsq[c] * invn - m * m;
        float a = pg[c] * rsqrtf(var + EPSV);
        ca[c] = a;
        cd[c] = pbt[c] - m * a;
    }
    if (t < 64) { red[0][t] = 0.f; red[1][t] = 0.f; }

    const int ar = t >> 1;          // A row 0..127
    const int acg = t & 1;          // col group (16 cols)
    float4 arv[4];

    auto LOADA = [&](int k0) {
        const float4* p = reinterpret_cast<const float4*>(
            Araw + (size_t)(m0 + ar) * K + k0 + acg * 16);
        arv[0] = p[0]; arv[1] = p[1]; arv[2] = p[2]; arv[3] = p[3];
    };
    auto WRITEA = [&](int buf, int k0) {
        int cb = k0 + acg * 16;
        float o[16];
#pragma unroll
        for (int jj = 0; jj < 4; ++jj) {
            float4 a4 = *reinterpret_cast<const float4*>(&ca[cb + jj * 4]);
            float4 d4 = *reinterpret_cast<const float4*>(&cd[cb + jj * 4]);
            float y0 = a4.x * arv[jj].x + d4.x;
            float y1 = a4.y * arv[jj].y + d4.y;
            float y2 = a4.z * arv[jj].z + d4.z;
            float y3 = a4.w * arv[jj].w + d4.w;
            o[jj * 4 + 0] = y0 > 0.f ? y0 : SLOPE * y0;
            o[jj * 4 + 1] = y1 > 0.f ? y1 : SLOPE * y1;
            o[jj * 4 + 2] = y2 > 0.f ? y2 : SLOPE * y2;
            o[jj * 4 + 3] = y3 > 0.f ? y3 : SLOPE * y3;
        }
        union { s16x8 v; unsigned u[4]; } lo, hi;
#pragma unroll
        for (int jj = 0; jj < 4; ++jj) {
            lo.u[jj] = cvt_pk_bf16(o[jj * 2], o[jj * 2 + 1]);
            hi.u[jj] = cvt_pk_bf16(o[8 + jj * 2], o[8 + jj * 2 + 1]);
        }
        char* base = (char*)&As[buf][0] + ar * 64;
        *reinterpret_cast<s16x8*>(base + (((acg * 2 + 0) ^ (ar & 3)) << 4)) = lo.v;
        *reinterpret_cast<s16x8*>(base + (((acg * 2 + 1) ^ (ar & 3)) << 4)) = hi.v;
    };
    auto STAGEB = [&](int buf, int k0) {
        GLOAD_LDS16(W + (size_t)(n0 + srow) * K + k0 + scol, &Bs[buf][t * 8]);
    };

    f32x4 acc[2][4];
#pragma unroll
    for (int fm = 0; fm < 2; ++fm)
#pragma unroll
        for (int fn = 0; fn < 4; ++fn) acc[fm][fn] = (f32x4){0.f, 0.f, 0.f, 0.f};

    LOADA(0);
    STAGEB(0, 0);
    __syncthreads();          // coef arrays ready (also covers red init)
    WRITEA(0, 0);
    __syncthreads();

    int cur = 0;
    for (int ks = 0; ks < KS; ++ks) {
        if (ks + 1 < KS) { STAGEB(cur ^ 1, (ks + 1) * 32); LOADA((ks + 1) * 32); }
        s16x8 b0 = *reinterpret_cast<const s16x8*>(&Bs[cur][(0 + la) * 32 + lks]);
        s16x8 b1 = *reinterpret_cast<const s16x8*>(&Bs[cur][(16 + la) * 32 + lks]);
        s16x8 b2 = *reinterpret_cast<const s16x8*>(&Bs[cur][(32 + la) * 32 + lks]);
        s16x8 b3 = *reinterpret_cast<const s16x8*>(&Bs[cur][(48 + la) * 32 + lks]);
#pragma unroll
        for (int fm = 0; fm < 2; ++fm) {
            s16x8 a = *reinterpret_cast<const s16x8*>(&As[cur][(w * 32 + fm * 16 + la) * 32 + lks]);
            acc[fm][0] = __builtin_amdgcn_mfma_f32_16x16x32_bf16(a, b0, acc[fm][0], 0, 0, 0);
            acc[fm][1] = __builtin_amdgcn_mfma_f32_16x16x32_bf16(a, b1, acc[fm][1], 0, 0, 0);
            acc[fm][2] = __builtin_amdgcn_mfma_f32_16x16x32_bf16(a, b2, acc[fm][2], 0, 0, 0);
            acc[fm][3] = __builtin_amdgcn_mfma_f32_16x16x32_bf16(a, b3, acc[fm][3], 0, 0, 0);
        }
        if (ks + 1 < KS) WRITEA(cur ^ 1, (ks + 1) * 32);
        __syncthreads();
        cur ^= 1;
    }

    float bv[4], s[4] = {}, q[4] = {};
#pragma unroll
    for (int fn = 0; fn < 4; ++fn) bv[fn] = bias[n0 + fn * 16 + la];
#pragma unroll
    for (int fm = 0; fm < 2; ++fm)
#pragma unroll
        for (int fn = 0; fn < 4; ++fn)
#pragma unroll
            for (int r = 0; r < 4; ++r) {
                int row = m0 + w * 32 + fm * 16 + (lane >> 4) * 4 + r;
                float v = acc[fm][fn][r] + bv[fn];
                C[(size_t)row * NC + n0 + fn * 16 + la] = v;
                s[fn] += v; q[fn] += v * v;
            }
#pragma unroll
    for (int fn = 0; fn < 4; ++fn) {
        s[fn] += __shfl_xor(s[fn], 16); s[fn] += __shfl_xor(s[fn], 32);
        q[fn] += __shfl_xor(q[fn], 16); q[fn] += __shfl_xor(q[fn], 32);
    }
    if (lane < 16) {
#pragma unroll
        for (int fn = 0; fn < 4; ++fn) {
            atomicAdd(&red[0][fn * 16 + lane], s[fn]);
            atomicAdd(&red[1][fn * 16 + lane], q[fn]);
        }
    }
    __syncthreads();
    if (t < 64) {
        atomicAdd(&sums[n0 + t], red[0][t]);
        atomicAdd(&sumsq[n0 + t], red[1][t]);
    }
}

// ---------------------------------------------------------------------------
// Dispatch 4: gemm3 with BN2 fused. BM=16, NC=64, 512 blocks, 4 waves
// (wave w owns output cols w*16..+15).
// ---------------------------------------------------------------------------
__global__ __launch_bounds__(256) void k_gemm3_bn(const float* __restrict__ Araw,
                                                  const ushort* __restrict__ W,
                                                  const float* __restrict__ bias,
                                                  const float* __restrict__ psum,
                                                  const float* __restrict__ psumsq,
                                                  const float* __restrict__ pg,
                                                  const float* __restrict__ pbt,
                                                  float* __restrict__ C,
                                                  float* __restrict__ sums,
                                                  float* __restrict__ sumsq) {
    constexpr int K = 512, KS = 16;
    __shared__ ushort As[2][512];
    __shared__ ushort Bs[2][2048];
    __shared__ float ca[K], cd[K];
    const int t = threadIdx.x;
    const int lane = t & 63;
    const int w = t >> 6;
    const int m0 = blockIdx.x * 16;
    const int la = lane & 15;
    const int lk = (lane >> 4) * 8;
    const int lks = lk ^ ((la & 3) << 3);
    const int srow = t >> 2;
    const int scol = ((t & 3) ^ (srow & 3)) * 8;
    const float invn = 1.f / (float)ROWS;

    for (int c = t; c < K; c += 256) {
        float m = psum[c] * invn;
        float var = psumsq[c] * invn - m * m;
        float a = pg[c] * rsqrtf(var + EPSV);
        ca[c] = a;
        cd[c] = pbt[c] - m * a;
    }

    const int ar = t >> 4;          // A row 0..15
    const int ac = (t & 15) * 2;    // col pair
    float2 arv;
    auto LOADA = [&](int k0) {
        arv = *reinterpret_cast<const float2*>(Araw + (size_t)(m0 + ar) * K + k0 + ac);
    };
    auto WRITEA = [&](int buf, int k0) {
        float a0 = ca[k0 + ac], a1 = ca[k0 + ac + 1];
        float d0 = cd[k0 + ac], d1 = cd[k0 + ac + 1];
        float y0 = a0 * arv.x + d0, y1 = a1 * arv.y + d1;
        y0 = y0 > 0.f ? y0 : SLOPE * y0;
        y1 = y1 > 0.f ? y1 : SLOPE * y1;
        unsigned pk = cvt_pk_bf16(y0, y1);
        char* base = (char*)&As[buf][0] + ar * 64;
        *reinterpret_cast<unsigned*>(base + ((((ac * 2) >> 4) ^ (ar & 3)) << 4) + ((ac * 2) & 15)) = pk;
    };
    auto STAGEB = [&](int buf, int k0) {
        GLOAD_LDS16(W + (size_t)srow * K + k0 + scol, &Bs[buf][t * 8]);
    };

    f32x4 acc = {0.f, 0.f, 0.f, 0.f};
    LOADA(0);
    STAGEB(0, 0);
    __syncthreads();     // coef ready
    WRITEA(0, 0);
    __syncthreads();

    int cur = 0;
    for (int ks = 0; ks < KS; ++ks) {
        if (ks + 1 < KS) { STAGEB(cur ^ 1, (ks + 1) * 32); LOADA((ks + 1) * 32); }
        s16x8 a = *reinterpret_cast<const s16x8*>(&As[cur][la * 32 + lks]);
        s16x8 bb = *reinterpret_cast<const s16x8*>(&Bs[cur][(w * 16 + la) * 32 + lks]);
        acc = __builtin_amdgcn_mfma_f32_16x16x32_bf16(a, bb, acc, 0, 0, 0);
        if (ks + 1 < KS) WRITEA(cur ^ 1, (ks + 1) * 32);
        __syncthreads();
        cur ^= 1;
    }

    float bv = bias[w * 16 + la];
    float s = 0.f, q = 0.f;
#pragma unroll
    for (int r = 0; r < 4; ++r) {
        int row = m0 + (lane >> 4) * 4 + r;
        float v = acc[r] + bv;
        C[(size_t)row * NO + w * 16 + la] = v;
        s += v; q += v * v;
    }
    s += __shfl_xor(s, 16); s += __shfl_xor(s, 32);
    q += __shfl_xor(q, 16); q += __shfl_xor(q, 32);
    if (lane < 16) {
        atomicAdd(&sums[w * 16 + la], s);
        atomicAdd(&sumsq[w * 16 + la], q);
    }
}

// ---------------------------------------------------------------------------
// Dispatch 5: final BN -> out (exact cover: 512 blocks x 256 thr x 1 float4).
// ---------------------------------------------------------------------------
__global__ __launch_bounds__(256) void k_bn3(const float* __restrict__ Yin,
                                             float* __restrict__ Yout,
                                             const float* __restrict__ sums,
                                             const float* __restrict__ sumsq,
                                             const float* __restrict__ g,
                                             const float* __restrict__ bt) {
    const float invn = 1.f / (float)ROWS;
    int e = blockIdx.x * 256 + threadIdx.x;
    int c0 = (e * 4) & (NO - 1);
    float4 v = reinterpret_cast<const float4*>(Yin)[e];
    float vv[4] = {v.x, v.y, v.z, v.w};
    float oo[4];
#pragma unroll
    for (int j = 0; j < 4; ++j) {
        int c = c0 + j;
        float m = sums[c] * invn;
        float var = sumsq[c] * invn - m * m;
        float rs = rsqrtf(var + EPSV);
        oo[j] = (vv[j] - m) * rs * g[c] + bt[c];
    }
    reinterpret_cast<float4*>(Yout)[e] = make_float4(oo[0], oo[1], oo[2], oo[3]);
}

extern "C" void kernel_launch(void* const* d_in, const int* in_sizes, int n_in,
                              void* d_out, int out_size, void* d_ws, size_t ws_size,
                              hipStream_t stream) {
    const float* x   = (const float*)d_in[0];
    const float* Q   = (const float*)d_in[1];
    const float* W1  = (const float*)d_in[2];
    const float* b1  = (const float*)d_in[3];
    const float* g1  = (const float*)d_in[4];
    const float* bt1 = (const float*)d_in[5];
    const float* W2  = (const float*)d_in[6];
    const float* b2  = (const float*)d_in[7];
    const float* g2  = (const float*)d_in[8];
    const float* bt2 = (const float*)d_in[9];
    const float* W3  = (const float*)d_in[10];
    const float* b3  = (const float*)d_in[11];
    const float* g3  = (const float*)d_in[12];
    const float* bt3 = (const float*)d_in[13];
    float* out = (float*)d_out;

    char* wsb = (char*)d_ws;
    ushort* Vb  = (ushort*)wsb;                      // [0,4M) bf16 8192x256
    float*  Yr3 = (float*)(wsb + (4u << 20));        // [4,6M) fp32 8192x64
    float*  Yr1 = (float*)(wsb + (16u << 20));       // [16,32M) fp32 8192x512
    float*  Yr2 = (float*)(wsb + (32u << 20));       // [32,48M) fp32 8192x512
    ushort* W1b = (ushort*)(wsb + (48u << 20));
    ushort* W2b = W1b + 512 * 256;
    ushort* W3b = W2b + 512 * 512;
    float*  st  = (float*)(W3b + 64 * 512);
    float* s1 = st;        float* q1 = s1 + 512;
    float* s2 = q1 + 512;  float* q2 = s2 + 512;
    float* s3 = q2 + 512;  float* q3 = s3 + 64;

    k_getv_wconv<<<1088, 256, 0, stream>>>(x, Q, Vb, W1, W2, W3, W1b, W2b, W3b, st);

    k_gemm1<<<dim3(8, 64), 256, 0, stream>>>(Vb, W1b, b1, Yr1, s1, q1);

    k_gemm_bn<512, 512><<<dim3(8, 64), 256, 0, stream>>>(
        Yr1, W2b, b2, s1, q1, g1, bt1, Yr2, s2, q2);

    k_gemm3_bn<<<512, 256, 0, stream>>>(
        Yr2, W3b, b3, s2, q2, g2, bt2, Yr3, s3, q3);

    k_bn3<<<512, 256, 0, stream>>>(Yr3, out, s3, q3, g3, bt3);
}

// Round 8
// 161.649 us; speedup vs baseline: 3.3041x; 1.0639x over previous
//
#include <hip/hip_runtime.h>

#define BB 16
#define NN 512
#define NI 32
#define NHEAD 8
#define NH 512
#define NO 64
#define ROWS (BB*NN)   // 8192
#define EPSV 1e-5f
#define SLOPE 0.05f

typedef __attribute__((ext_vector_type(4))) float f32x4;
typedef __attribute__((ext_vector_type(8))) short s16x8;

static __device__ __forceinline__ ushort f2bf(float f) {
    union { float f; unsigned u; } v; v.f = f;
    unsigned r = v.u + 0x7fff + ((v.u >> 16) & 1);   // RNE
    return (ushort)(r >> 16);
}

static __device__ __forceinline__ unsigned cvt_pk_bf16(float lo, float hi) {
    unsigned r;
    asm("v_cvt_pk_bf16_f32 %0, %1, %2" : "=v"(r) : "v"(lo), "v"(hi));
    return r;
}

static __device__ __forceinline__ float bf2f(ushort u) {
    union { unsigned u; float f; } v; v.u = ((unsigned)u) << 16;
    return v.f;
}

#define GLOAD_LDS16(g, l) __builtin_amdgcn_global_load_lds( \
    (const __attribute__((address_space(1))) void*)(g),     \
    (__attribute__((address_space(3))) void*)(l), 16, 0, 0)

// getv x^T tile swizzle (ushort index space).
#define XTI(i, m) ((((i) * 512) + (m)) ^ (((i) & 7) << 3))

// ---------------------------------------------------------------------------
// Dispatch 1: blocks [0,512) = getv, 2 tiles per block (staging amortized 2x,
// packed ds_write_b64 staging); blocks [512,576) = wconv + stats zero.
// ---------------------------------------------------------------------------
__global__ __launch_bounds__(256, 2) void k_getv_wconv(
    const float* __restrict__ x, const float* __restrict__ Qm,
    ushort* __restrict__ Vb,
    const float* __restrict__ W1, const float* __restrict__ W2,
    const float* __restrict__ W3,
    ushort* __restrict__ W1b, ushort* __restrict__ W2b, ushort* __restrict__ W3b,
    float* __restrict__ st) {
    const int blk = blockIdx.x;
    const int t = threadIdx.x;

    if (blk >= 512) {   // wconv + stats-zero
        const int gid = (blk - 512) * 256 + t;   // 0..16383
        if (gid < 2176) st[gid] = 0.f;
#pragma unroll
        for (int r = 0; r < 2; ++r) {
            int i = gid + r * 16384;
            if (i < 32768) {
                float4 v = reinterpret_cast<const float4*>(W1)[i];
                *reinterpret_cast<ushort4*>(W1b + (size_t)i * 4) =
                    make_ushort4(f2bf(v.x), f2bf(v.y), f2bf(v.z), f2bf(v.w));
            }
        }
#pragma unroll
        for (int r = 0; r < 4; ++r) {
            int i = gid + r * 16384;
            float4 v = reinterpret_cast<const float4*>(W2)[i];
            *reinterpret_cast<ushort4*>(W2b + (size_t)i * 4) =
                make_ushort4(f2bf(v.x), f2bf(v.y), f2bf(v.z), f2bf(v.w));
        }
        if (gid < 8192) {
            float4 v = reinterpret_cast<const float4*>(W3)[gid];
            *reinterpret_cast<ushort4*>(W3b + (size_t)gid * 4) =
                make_ushort4(f2bf(v.x), f2bf(v.y), f2bf(v.z), f2bf(v.w));
        }
        return;
    }

    __shared__ ushort xT[32 * 512];   // 32 KB, swizzled [i][m]
    __shared__ float poss[NN * 4];    // 8 KB
    const int b = blk >> 5;
    const int tpair = blk & 31;
    const int lane = t & 63;
    const int w = t >> 6;

    // ---- staging: thread owns i4 = t&7 (4 cols), m-quads (t>>3)+j*32 ----
    const float4* xg = reinterpret_cast<const float4*>(x + (size_t)b * NN * NI);
    const int i4 = t & 7;
#pragma unroll
    for (int j = 0; j < 4; ++j) {
        int m0 = ((t >> 3) + j * 32) * 4;          // 0..508, step 4
        float4 a0 = xg[(m0 + 0) * 8 + i4];
        float4 a1 = xg[(m0 + 1) * 8 + i4];
        float4 a2 = xg[(m0 + 2) * 8 + i4];
        float4 a3 = xg[(m0 + 3) * 8 + i4];
        uint2 p;
        p = make_uint2(cvt_pk_bf16(a0.x, a1.x), cvt_pk_bf16(a2.x, a3.x));
        *reinterpret_cast<uint2*>(&xT[XTI(i4 * 4 + 0, m0)]) = p;
        p = make_uint2(cvt_pk_bf16(a0.y, a1.y), cvt_pk_bf16(a2.y, a3.y));
        *reinterpret_cast<uint2*>(&xT[XTI(i4 * 4 + 1, m0)]) = p;
        p = make_uint2(cvt_pk_bf16(a0.z, a1.z), cvt_pk_bf16(a2.z, a3.z));
        *reinterpret_cast<uint2*>(&xT[XTI(i4 * 4 + 2, m0)]) = p;
        p = make_uint2(cvt_pk_bf16(a0.w, a1.w), cvt_pk_bf16(a2.w, a3.w));
        *reinterpret_cast<uint2*>(&xT[XTI(i4 * 4 + 3, m0)]) = p;
        if (i4 == 0) {
            *reinterpret_cast<float4*>(&poss[(m0 + 0) * 4]) = a0;
            *reinterpret_cast<float4*>(&poss[(m0 + 1) * 4]) = a1;
            *reinterpret_cast<float4*>(&poss[(m0 + 2) * 4]) = a2;
            *reinterpret_cast<float4*>(&poss[(m0 + 3) * 4]) = a3;
        }
    }
    __syncthreads();

    const int la = lane & 15;
    const int mko = (lane >> 4) * 8;
#pragma unroll 1
    for (int rep = 0; rep < 2; ++rep) {
        const int tile = tpair * 2 + rep;          // 0..63
        const int h = tile >> 3;
        const int nb = (tile & 7) * 64;
        const float qx = Qm[h * 3 + 0], qy = Qm[h * 3 + 1], qz = Qm[h * 3 + 2];
        const int n_a = nb + w * 16 + la;
        float4 pa = *reinterpret_cast<const float4*>(&poss[n_a * 4]);
        const float c0 = pa.x - qx, c1 = pa.y - qy, c2 = pa.z - qz;

        f32x4 acc0 = {0.f, 0.f, 0.f, 0.f}, acc1 = {0.f, 0.f, 0.f, 0.f};
        for (int mc = 0; mc < NN; mc += 32) {
            float d[8];
#pragma unroll
            for (int j = 0; j < 8; ++j) {
                float4 pm = *reinterpret_cast<const float4*>(&poss[(mc + mko + j) * 4]);
                float t0 = c0 - pm.x, t1 = c1 - pm.y, t2 = c2 - pm.z;
                float e = fmaf(t0, t0, fmaf(t1, t1, t2 * t2));
                d[j] = exp2f(e * -1.4426950408889634f);
            }
            union { s16x8 v; unsigned u[4]; } af;
#pragma unroll
            for (int j = 0; j < 4; ++j) af.u[j] = cvt_pk_bf16(d[2 * j], d[2 * j + 1]);
            s16x8 bb0 = *reinterpret_cast<const s16x8*>(&xT[XTI(la, mc + mko)]);
            s16x8 bb1 = *reinterpret_cast<const s16x8*>(&xT[XTI(la + 16, mc + mko)]);
            acc0 = __builtin_amdgcn_mfma_f32_16x16x32_bf16(af.v, bb0, acc0, 0, 0, 0);
            acc1 = __builtin_amdgcn_mfma_f32_16x16x32_bf16(af.v, bb1, acc1, 0, 0, 0);
        }
        const int i = la;
#pragma unroll
        for (int r = 0; r < 4; ++r) {
            int n = nb + w * 16 + (lane >> 4) * 4 + r;
            float v0 = acc0[r], v1 = acc1[r];
            if (i < 3) {
                const float* p = &poss[n * 4];
                v0 -= (i == 0) ? p[0] : (i == 1) ? p[1] : p[2];
            }
            ushort* vp = Vb + (((size_t)(b * NN + n)) * NHEAD + h) * NI;
            vp[i] = f2bf(v0);
            vp[i + 16] = f2bf(v1);
        }
    }
}

// ---------------------------------------------------------------------------
// Dispatch 2: gemm1. A bf16 (V), gload_lds staging, BM=128, fused stats.
// C written as bf16 RAW (pre-BN); stats from fp32 accs.
// ---------------------------------------------------------------------------
__global__ __launch_bounds__(256) void k_gemm1(const ushort* __restrict__ A,
                                               const ushort* __restrict__ W,
                                               const float* __restrict__ bias,
                                               ushort* __restrict__ Cb,
                                               float* __restrict__ sums,
                                               float* __restrict__ sumsq) {
    constexpr int K = 256, NC = 512, KS = K / 32;
    __shared__ ushort As[2][4096];
    __shared__ ushort Bs[2][2048];
    __shared__ float red[2][64];
    const int t = threadIdx.x;
    const int lane = t & 63;
    const int w = t >> 6;
    const int m0 = blockIdx.y * 128;
    const int n0 = blockIdx.x * 64;
    const int la = lane & 15;
    const int lk = (lane >> 4) * 8;
    const int lks = lk ^ ((la & 3) << 3);
    const int srow = t >> 2;
    const int scol = ((t & 3) ^ (srow & 3)) * 8;

    if (t < 64) { red[0][t] = 0.f; red[1][t] = 0.f; }

    f32x4 acc[2][4];
#pragma unroll
    for (int fm = 0; fm < 2; ++fm)
#pragma unroll
        for (int fn = 0; fn < 4; ++fn) acc[fm][fn] = (f32x4){0.f, 0.f, 0.f, 0.f};

    auto STAGE = [&](int buf, int k0) {
        GLOAD_LDS16(A + (size_t)(m0 + srow) * K + k0 + scol, &As[buf][t * 8]);
        GLOAD_LDS16(A + (size_t)(m0 + 64 + srow) * K + k0 + scol, &As[buf][2048 + t * 8]);
        GLOAD_LDS16(W + (size_t)(n0 + srow) * K + k0 + scol, &Bs[buf][t * 8]);
    };

    STAGE(0, 0);
    __syncthreads();
    int cur = 0;
    for (int ks = 0; ks < KS; ++ks) {
        if (ks + 1 < KS) STAGE(cur ^ 1, (ks + 1) * 32);
        s16x8 b0 = *reinterpret_cast<const s16x8*>(&Bs[cur][(0 + la) * 32 + lks]);
        s16x8 b1 = *reinterpret_cast<const s16x8*>(&Bs[cur][(16 + la) * 32 + lks]);
        s16x8 b2 = *reinterpret_cast<const s16x8*>(&Bs[cur][(32 + la) * 32 + lks]);
        s16x8 b3 = *reinterpret_cast<const s16x8*>(&Bs[cur][(48 + la) * 32 + lks]);
#pragma unroll
        for (int fm = 0; fm < 2; ++fm) {
            s16x8 a = *reinterpret_cast<const s16x8*>(&As[cur][(w * 32 + fm * 16 + la) * 32 + lks]);
            acc[fm][0] = __builtin_amdgcn_mfma_f32_16x16x32_bf16(a, b0, acc[fm][0], 0, 0, 0);
            acc[fm][1] = __builtin_amdgcn_mfma_f32_16x16x32_bf16(a, b1, acc[fm][1], 0, 0, 0);
            acc[fm][2] = __builtin_amdgcn_mfma_f32_16x16x32_bf16(a, b2, acc[fm][2], 0, 0, 0);
            acc[fm][3] = __builtin_amdgcn_mfma_f32_16x16x32_bf16(a, b3, acc[fm][3], 0, 0, 0);
        }
        __syncthreads();
        cur ^= 1;
    }

    float bv[4], s[4] = {}, q[4] = {};
#pragma unroll
    for (int fn = 0; fn < 4; ++fn) bv[fn] = bias[n0 + fn * 16 + la];
#pragma unroll
    for (int fm = 0; fm < 2; ++fm)
#pragma unroll
        for (int fn = 0; fn < 4; ++fn)
#pragma unroll
            for (int r = 0; r < 4; ++r) {
                int row = m0 + w * 32 + fm * 16 + (lane >> 4) * 4 + r;
                float v = acc[fm][fn][r] + bv[fn];
                Cb[(size_t)row * NC + n0 + fn * 16 + la] = f2bf(v);
                s[fn] += v; q[fn] += v * v;
            }
#pragma unroll
    for (int fn = 0; fn < 4; ++fn) {
        s[fn] += __shfl_xor(s[fn], 16); s[fn] += __shfl_xor(s[fn], 32);
        q[fn] += __shfl_xor(q[fn], 16); q[fn] += __shfl_xor(q[fn], 32);
    }
    if (lane < 16) {
#pragma unroll
        for (int fn = 0; fn < 4; ++fn) {
            atomicAdd(&red[0][fn * 16 + lane], s[fn]);
            atomicAdd(&red[1][fn * 16 + lane], q[fn]);
        }
    }
    __syncthreads();
    if (t < 64) {
        atomicAdd(&sums[n0 + t], red[0][t]);
        atomicAdd(&sumsq[n0 + t], red[1][t]);
    }
}

// ---------------------------------------------------------------------------
// Dispatch 3: gemm2. A = bf16 RAW prev-layer output (gload_lds staged);
// BN affine + leaky applied IN-REGISTER after ds_read, before MFMA.
// C written as bf16 RAW + fused stats.
// ---------------------------------------------------------------------------
template <int K, int NC>
__global__ __launch_bounds__(256) void k_gemm_bn(const ushort* __restrict__ Araw,
                                                 const ushort* __restrict__ W,
                                                 const float* __restrict__ bias,
                                                 const float* __restrict__ psum,
                                                 const float* __restrict__ psumsq,
                                                 const float* __restrict__ pg,
                                                 const float* __restrict__ pbt,
                                                 ushort* __restrict__ Cb,
                                                 float* __restrict__ sums,
                                                 float* __restrict__ sumsq) {
    constexpr int KS = K / 32;
    __shared__ ushort As[2][4096];
    __shared__ ushort Bs[2][2048];
    __shared__ float ca[K], cd[K];
    __shared__ float red[2][64];
    const int t = threadIdx.x;
    const int lane = t & 63;
    const int w = t >> 6;
    const int m0 = blockIdx.y * 128;
    const int n0 = blockIdx.x * 64;
    const int la = lane & 15;
    const int lk = (lane >> 4) * 8;
    const int lks = lk ^ ((la & 3) << 3);
    const int srow = t >> 2;
    const int scol = ((t & 3) ^ (srow & 3)) * 8;
    const float invn = 1.f / (float)ROWS;

    for (int c = t; c < K; c += 256) {
        float m = psum[c] * invn;
        float var = psumsq[c] * invn - m * m;
        float a = pg[c] * rsqrtf(var + EPSV);
        ca[c] = a;
        cd[c] = pbt[c] - m * a;
    }
    if (t < 64) { red[0][t] = 0.f; red[1][t] = 0.f; }

    auto STAGE = [&](int buf, int k0) {
        GLOAD_LDS16(Araw + (size_t)(m0 + srow) * K + k0 + scol, &As[buf][t * 8]);
        GLOAD_LDS16(Araw + (size_t)(m0 + 64 + srow) * K + k0 + scol, &As[buf][2048 + t * 8]);
        GLOAD_LDS16(W + (size_t)(n0 + srow) * K + k0 + scol, &Bs[buf][t * 8]);
    };

    f32x4 acc[2][4];
#pragma unroll
    for (int fm = 0; fm < 2; ++fm)
#pragma unroll
        for (int fn = 0; fn < 4; ++fn) acc[fm][fn] = (f32x4){0.f, 0.f, 0.f, 0.f};

    STAGE(0, 0);
    __syncthreads();           // covers ca/cd + staged data
    int cur = 0;
    for (int ks = 0; ks < KS; ++ks) {
        const int k0 = ks * 32;
        if (ks + 1 < KS) STAGE(cur ^ 1, (ks + 1) * 32);
        s16x8 b0 = *reinterpret_cast<const s16x8*>(&Bs[cur][(0 + la) * 32 + lks]);
        s16x8 b1 = *reinterpret_cast<const s16x8*>(&Bs[cur][(16 + la) * 32 + lks]);
        s16x8 b2 = *reinterpret_cast<const s16x8*>(&Bs[cur][(32 + la) * 32 + lks]);
        s16x8 b3 = *reinterpret_cast<const s16x8*>(&Bs[cur][(48 + la) * 32 + lks]);
        // BN coefs for this k-slice (broadcast reads within 16-lane groups)
        float4 ka0 = *reinterpret_cast<const float4*>(&ca[k0 + lk]);
        float4 ka1 = *reinterpret_cast<const float4*>(&ca[k0 + lk + 4]);
        float4 kd0 = *reinterpret_cast<const float4*>(&cd[k0 + lk]);
        float4 kd1 = *reinterpret_cast<const float4*>(&cd[k0 + lk + 4]);
        float kaf[8] = {ka0.x, ka0.y, ka0.z, ka0.w, ka1.x, ka1.y, ka1.z, ka1.w};
        float kdf[8] = {kd0.x, kd0.y, kd0.z, kd0.w, kd1.x, kd1.y, kd1.z, kd1.w};
#pragma unroll
        for (int fm = 0; fm < 2; ++fm) {
            union { s16x8 v; ushort us[8]; } araw;
            araw.v = *reinterpret_cast<const s16x8*>(&As[cur][(w * 32 + fm * 16 + la) * 32 + lks]);
            float y[8];
#pragma unroll
            for (int e = 0; e < 8; ++e) {
                float f = bf2f(araw.us[e]);
                float z = fmaf(kaf[e], f, kdf[e]);
                y[e] = fmaxf(z, 0.f) + SLOPE * fminf(z, 0.f);
            }
            union { s16x8 v; unsigned u[4]; } af;
#pragma unroll
            for (int p = 0; p < 4; ++p) af.u[p] = cvt_pk_bf16(y[2 * p], y[2 * p + 1]);
            acc[fm][0] = __builtin_amdgcn_mfma_f32_16x16x32_bf16(af.v, b0, acc[fm][0], 0, 0, 0);
            acc[fm][1] = __builtin_amdgcn_mfma_f32_16x16x32_bf16(af.v, b1, acc[fm][1], 0, 0, 0);
            acc[fm][2] = __builtin_amdgcn_mfma_f32_16x16x32_bf16(af.v, b2, acc[fm][2], 0, 0, 0);
            acc[fm][3] = __builtin_amdgcn_mfma_f32_16x16x32_bf16(af.v, b3, acc[fm][3], 0, 0, 0);
        }
        __syncthreads();
        cur ^= 1;
    }

    float bv[4], s[4] = {}, q[4] = {};
#pragma unroll
    for (int fn = 0; fn < 4; ++fn) bv[fn] = bias[n0 + fn * 16 + la];
#pragma unroll
    for (int fm = 0; fm < 2; ++fm)
#pragma unroll
        for (int fn = 0; fn < 4; ++fn)
#pragma unroll
            for (int r = 0; r < 4; ++r) {
                int row = m0 + w * 32 + fm * 16 + (lane >> 4) * 4 + r;
                float v = acc[fm][fn][r] + bv[fn];
                Cb[(size_t)row * NC + n0 + fn * 16 + la] = f2bf(v);
                s[fn] += v; q[fn] += v * v;
            }
#pragma unroll
    for (int fn = 0; fn < 4; ++fn) {
        s[fn] += __shfl_xor(s[fn], 16); s[fn] += __shfl_xor(s[fn], 32);
        q[fn] += __shfl_xor(q[fn], 16); q[fn] += __shfl_xor(q[fn], 32);
    }
    if (lane < 16) {
#pragma unroll
        for (int fn = 0; fn < 4; ++fn) {
            atomicAdd(&red[0][fn * 16 + lane], s[fn]);
            atomicAdd(&red[1][fn * 16 + lane], q[fn]);
        }
    }
    __syncthreads();
    if (t < 64) {
        atomicAdd(&sums[n0 + t], red[0][t]);
        atomicAdd(&sumsq[n0 + t], red[1][t]);
    }
}

// ---------------------------------------------------------------------------
// Dispatch 4: gemm3. A = bf16 RAW Y2 (16x32 tile staged by wave 0),
// BN2+leaky in-register post-ds_read; C fp32 + stats.
// ---------------------------------------------------------------------------
__global__ __launch_bounds__(256) void k_gemm3_bn(const ushort* __restrict__ Araw,
                                                  const ushort* __restrict__ W,
                                                  const float* __restrict__ bias,
                                                  const float* __restrict__ psum,
                                                  const float* __restrict__ psumsq,
                                                  const float* __restrict__ pg,
                                                  const float* __restrict__ pbt,
                                                  float* __restrict__ C,
                                                  float* __restrict__ sums,
                                                  float* __restrict__ sumsq) {
    constexpr int K = 512, KS = 16;
    __shared__ ushort As[2][512];
    __shared__ ushort Bs[2][2048];
    __shared__ float ca[K], cd[K];
    const int t = threadIdx.x;
    const int lane = t & 63;
    const int w = t >> 6;
    const int m0 = blockIdx.x * 16;
    const int la = lane & 15;
    const int lk = (lane >> 4) * 8;
    const int lks = lk ^ ((la & 3) << 3);
    const int srow = t >> 2;
    const int scol = ((t & 3) ^ (srow & 3)) * 8;
    const int srow3 = lane >> 2;
    const int scol3 = ((lane & 3) ^ (srow3 & 3)) * 8;
    const float invn = 1.f / (float)ROWS;

    for (int c = t; c < K; c += 256) {
        float m = psum[c] * invn;
        float var = psumsq[c] * invn - m * m;
        float a = pg[c] * rsqrtf(var + EPSV);
        ca[c] = a;
        cd[c] = pbt[c] - m * a;
    }

    auto STAGE = [&](int buf, int k0) {
        if (w == 0)
            GLOAD_LDS16(Araw + (size_t)(m0 + srow3) * K + k0 + scol3, &As[buf][lane * 8]);
        GLOAD_LDS16(W + (size_t)srow * K + k0 + scol, &Bs[buf][t * 8]);
    };

    f32x4 acc = {0.f, 0.f, 0.f, 0.f};
    STAGE(0, 0);
    __syncthreads();
    int cur = 0;
    for (int ks = 0; ks < KS; ++ks) {
        const int k0 = ks * 32;
        if (ks + 1 < KS) STAGE(cur ^ 1, (ks + 1) * 32);
        float4 ka0 = *reinterpret_cast<const float4*>(&ca[k0 + lk]);
        float4 ka1 = *reinterpret_cast<const float4*>(&ca[k0 + lk + 4]);
        float4 kd0 = *reinterpret_cast<const float4*>(&cd[k0 + lk]);
        float4 kd1 = *reinterpret_cast<const float4*>(&cd[k0 + lk + 4]);
        float kaf[8] = {ka0.x, ka0.y, ka0.z, ka0.w, ka1.x, ka1.y, ka1.z, ka1.w};
        float kdf[8] = {kd0.x, kd0.y, kd0.z, kd0.w, kd1.x, kd1.y, kd1.z, kd1.w};
        union { s16x8 v; ushort us[8]; } araw;
        araw.v = *reinterpret_cast<const s16x8*>(&As[cur][la * 32 + lks]);
        float y[8];
#pragma unroll
        for (int e = 0; e < 8; ++e) {
            float f = bf2f(araw.us[e]);
            float z = fmaf(kaf[e], f, kdf[e]);
            y[e] = fmaxf(z, 0.f) + SLOPE * fminf(z, 0.f);
        }
        union { s16x8 v; unsigned u[4]; } af;
#pragma unroll
        for (int p = 0; p < 4; ++p) af.u[p] = cvt_pk_bf16(y[2 * p], y[2 * p + 1]);
        s16x8 bb = *reinterpret_cast<const s16x8*>(&Bs[cur][(w * 16 + la) * 32 + lks]);
        acc = __builtin_amdgcn_mfma_f32_16x16x32_bf16(af.v, bb, acc, 0, 0, 0);
        __syncthreads();
        cur ^= 1;
    }

    float bv = bias[w * 16 + la];
    float s = 0.f, q = 0.f;
#pragma unroll
    for (int r = 0; r < 4; ++r) {
        int row = m0 + (lane >> 4) * 4 + r;
        float v = acc[r] + bv;
        C[(size_t)row * NO + w * 16 + la] = v;
        s += v; q += v * v;
    }
    s += __shfl_xor(s, 16); s += __shfl_xor(s, 32);
    q += __shfl_xor(q, 16); q += __shfl_xor(q, 32);
    if (lane < 16) {
        atomicAdd(&sums[w * 16 + la], s);
        atomicAdd(&sumsq[w * 16 + la], q);
    }
}

// ---------------------------------------------------------------------------
// Dispatch 5: final BN -> out.
// ---------------------------------------------------------------------------
__global__ __launch_bounds__(256) void k_bn3(const float* __restrict__ Yin,
                                             float* __restrict__ Yout,
                                             const float* __restrict__ sums,
                                             const float* __restrict__ sumsq,
                                             const float* __restrict__ g,
                                             const float* __restrict__ bt) {
    const float invn = 1.f / (float)ROWS;
    int e = blockIdx.x * 256 + threadIdx.x;
    int c0 = (e * 4) & (NO - 1);
    float4 v = reinterpret_cast<const float4*>(Yin)[e];
    float vv[4] = {v.x, v.y, v.z, v.w};
    float oo[4];
#pragma unroll
    for (int j = 0; j < 4; ++j) {
        int c = c0 + j;
        float m = sums[c] * invn;
        float var = sumsq[c] * invn - m * m;
        float rs = rsqrtf(var + EPSV);
        oo[j] = (vv[j] - m) * rs * g[c] + bt[c];
    }
    reinterpret_cast<float4*>(Yout)[e] = make_float4(oo[0], oo[1], oo[2], oo[3]);
}

extern "C" void kernel_launch(void* const* d_in, const int* in_sizes, int n_in,
                              void* d_out, int out_size, void* d_ws, size_t ws_size,
                              hipStream_t stream) {
    const float* x   = (const float*)d_in[0];
    const float* Q   = (const float*)d_in[1];
    const float* W1  = (const float*)d_in[2];
    const float* b1  = (const float*)d_in[3];
    const float* g1  = (const float*)d_in[4];
    const float* bt1 = (const float*)d_in[5];
    const float* W2  = (const float*)d_in[6];
    const float* b2  = (const float*)d_in[7];
    const float* g2  = (const float*)d_in[8];
    const float* bt2 = (const float*)d_in[9];
    const float* W3  = (const float*)d_in[10];
    const float* b3  = (const float*)d_in[11];
    const float* g3  = (const float*)d_in[12];
    const float* bt3 = (const float*)d_in[13];
    float* out = (float*)d_out;

    char* wsb = (char*)d_ws;
    ushort* Vb   = (ushort*)wsb;                     // [0,4M)   bf16 8192x256
    ushort* Y1rb = (ushort*)(wsb + (4u << 20));      // [4,12M)  bf16 raw 8192x512
    ushort* Y2rb = (ushort*)(wsb + (12u << 20));     // [12,20M) bf16 raw 8192x512
    float*  Yr3  = (float*)(wsb + (20u << 20));      // [20,22M) fp32 8192x64
    ushort* W1b  = (ushort*)(wsb + (24u << 20));
    ushort* W2b  = W1b + 512 * 256;
    ushort* W3b  = W2b + 512 * 512;
    float*  st   = (float*)(W3b + 64 * 512);
    float* s1 = st;        float* q1 = s1 + 512;
    float* s2 = q1 + 512;  float* q2 = s2 + 512;
    float* s3 = q2 + 512;  float* q3 = s3 + 64;

    k_getv_wconv<<<576, 256, 0, stream>>>(x, Q, Vb, W1, W2, W3, W1b, W2b, W3b, st);

    k_gemm1<<<dim3(8, 64), 256, 0, stream>>>(Vb, W1b, b1, Y1rb, s1, q1);

    k_gemm_bn<512, 512><<<dim3(8, 64), 256, 0, stream>>>(
        Y1rb, W2b, b2, s1, q1, g1, bt1, Y2rb, s2, q2);

    k_gemm3_bn<<<512, 256, 0, stream>>>(
        Y2rb, W3b, b3, s2, q2, g2, bt2, Yr3, s3, q3);

    k_bn3<<<512, 256, 0, stream>>>(Yr3, out, s3, q3, g3, bt3);
}

// Round 9
// 154.092 us; speedup vs baseline: 3.4662x; 1.0490x over previous
//
#include <hip/hip_runtime.h>

#define BB 16
#define NN 512
#define NI 32
#define NHEAD 8
#define NH 512
#define NO 64
#define ROWS (BB*NN)   // 8192
#define EPSV 1e-5f
#define SLOPE 0.05f

typedef __attribute__((ext_vector_type(4))) float f32x4;
typedef __attribute__((ext_vector_type(8))) short s16x8;

static __device__ __forceinline__ ushort f2bf(float f) {
    union { float f; unsigned u; } v; v.f = f;
    unsigned r = v.u + 0x7fff + ((v.u >> 16) & 1);   // RNE
    return (ushort)(r >> 16);
}

static __device__ __forceinline__ unsigned cvt_pk_bf16(float lo, float hi) {
    unsigned r;
    asm("v_cvt_pk_bf16_f32 %0, %1, %2" : "=v"(r) : "v"(lo), "v"(hi));
    return r;
}

static __device__ __forceinline__ float bf2f(ushort u) {
    union { unsigned u; float f; } v; v.u = ((unsigned)u) << 16;
    return v.f;
}

#define GLOAD_LDS16(g, l) __builtin_amdgcn_global_load_lds( \
    (const __attribute__((address_space(1))) void*)(g),     \
    (__attribute__((address_space(3))) void*)(l), 16, 0, 0)

// getv x^T tile swizzle (ushort index space).
#define XTI(i, m) ((((i) * 512) + (m)) ^ (((i) & 7) << 3))

#define NL2 (-1.4426950408889634f)   // -log2(e)
#define PL2 (2.8853901617779268f)    //  2*log2(e)

// ---------------------------------------------------------------------------
// Dispatch 1: blocks [0,512) = getv, 2 tiles per block; blocks [512,576) =
// wconv + stats zero. D-exponent in expanded form:
//   arg = base + pmt[m] + sx*px + sy*py + sz*pz   (4 VALU + exp per element)
// pmt[m] = -log2e*|p_m|^2 lives in poss[m].w (feature x[m][3] only needed
// for xT, written before the overwrite).
// ---------------------------------------------------------------------------
__global__ __launch_bounds__(256, 2) void k_getv_wconv(
    const float* __restrict__ x, const float* __restrict__ Qm,
    ushort* __restrict__ Vb,
    const float* __restrict__ W1, const float* __restrict__ W2,
    const float* __restrict__ W3,
    ushort* __restrict__ W1b, ushort* __restrict__ W2b, ushort* __restrict__ W3b,
    float* __restrict__ st) {
    const int blk = blockIdx.x;
    const int t = threadIdx.x;

    if (blk >= 512) {   // wconv + stats-zero
        const int gid = (blk - 512) * 256 + t;   // 0..16383
        if (gid < 2176) st[gid] = 0.f;
#pragma unroll
        for (int r = 0; r < 2; ++r) {
            int i = gid + r * 16384;
            if (i < 32768) {
                float4 v = reinterpret_cast<const float4*>(W1)[i];
                *reinterpret_cast<ushort4*>(W1b + (size_t)i * 4) =
                    make_ushort4(f2bf(v.x), f2bf(v.y), f2bf(v.z), f2bf(v.w));
            }
        }
#pragma unroll
        for (int r = 0; r < 4; ++r) {
            int i = gid + r * 16384;
            float4 v = reinterpret_cast<const float4*>(W2)[i];
            *reinterpret_cast<ushort4*>(W2b + (size_t)i * 4) =
                make_ushort4(f2bf(v.x), f2bf(v.y), f2bf(v.z), f2bf(v.w));
        }
        if (gid < 8192) {
            float4 v = reinterpret_cast<const float4*>(W3)[gid];
            *reinterpret_cast<ushort4*>(W3b + (size_t)gid * 4) =
                make_ushort4(f2bf(v.x), f2bf(v.y), f2bf(v.z), f2bf(v.w));
        }
        return;
    }

    __shared__ ushort xT[32 * 512];   // 32 KB, swizzled [i][m]
    __shared__ float poss[NN * 4];    // 8 KB: (px,py,pz,pmt)
    const int b = blk >> 5;
    const int tpair = blk & 31;
    const int lane = t & 63;
    const int w = t >> 6;

    // ---- staging: thread owns i4 = t&7 (4 cols), m-quads (t>>3)+j*32 ----
    const float4* xg = reinterpret_cast<const float4*>(x + (size_t)b * NN * NI);
    const int i4 = t & 7;
#pragma unroll
    for (int j = 0; j < 4; ++j) {
        int m0 = ((t >> 3) + j * 32) * 4;          // 0..508, step 4
        float4 a0 = xg[(m0 + 0) * 8 + i4];
        float4 a1 = xg[(m0 + 1) * 8 + i4];
        float4 a2 = xg[(m0 + 2) * 8 + i4];
        float4 a3 = xg[(m0 + 3) * 8 + i4];
        uint2 p;
        p = make_uint2(cvt_pk_bf16(a0.x, a1.x), cvt_pk_bf16(a2.x, a3.x));
        *reinterpret_cast<uint2*>(&xT[XTI(i4 * 4 + 0, m0)]) = p;
        p = make_uint2(cvt_pk_bf16(a0.y, a1.y), cvt_pk_bf16(a2.y, a3.y));
        *reinterpret_cast<uint2*>(&xT[XTI(i4 * 4 + 1, m0)]) = p;
        p = make_uint2(cvt_pk_bf16(a0.z, a1.z), cvt_pk_bf16(a2.z, a3.z));
        *reinterpret_cast<uint2*>(&xT[XTI(i4 * 4 + 2, m0)]) = p;
        p = make_uint2(cvt_pk_bf16(a0.w, a1.w), cvt_pk_bf16(a2.w, a3.w));
        *reinterpret_cast<uint2*>(&xT[XTI(i4 * 4 + 3, m0)]) = p;
        if (i4 == 0) {
            *reinterpret_cast<float4*>(&poss[(m0 + 0) * 4]) = make_float4(
                a0.x, a0.y, a0.z, NL2 * fmaf(a0.x, a0.x, fmaf(a0.y, a0.y, a0.z * a0.z)));
            *reinterpret_cast<float4*>(&poss[(m0 + 1) * 4]) = make_float4(
                a1.x, a1.y, a1.z, NL2 * fmaf(a1.x, a1.x, fmaf(a1.y, a1.y, a1.z * a1.z)));
            *reinterpret_cast<float4*>(&poss[(m0 + 2) * 4]) = make_float4(
                a2.x, a2.y, a2.z, NL2 * fmaf(a2.x, a2.x, fmaf(a2.y, a2.y, a2.z * a2.z)));
            *reinterpret_cast<float4*>(&poss[(m0 + 3) * 4]) = make_float4(
                a3.x, a3.y, a3.z, NL2 * fmaf(a3.x, a3.x, fmaf(a3.y, a3.y, a3.z * a3.z)));
        }
    }
    __syncthreads();

    const int la = lane & 15;
    const int mko = (lane >> 4) * 8;
#pragma unroll 1
    for (int rep = 0; rep < 2; ++rep) {
        const int tile = tpair * 2 + rep;          // 0..63
        const int h = tile >> 3;
        const int nb = (tile & 7) * 64;
        const float qx = Qm[h * 3 + 0], qy = Qm[h * 3 + 1], qz = Qm[h * 3 + 2];
        const int n_a = nb + w * 16 + la;
        float4 pa = *reinterpret_cast<const float4*>(&poss[n_a * 4]);
        const float c0 = pa.x - qx, c1 = pa.y - qy, c2 = pa.z - qz;
        const float sx = PL2 * c0, sy = PL2 * c1, sz = PL2 * c2;
        const float base = NL2 * fmaf(c0, c0, fmaf(c1, c1, c2 * c2));

        f32x4 acc0 = {0.f, 0.f, 0.f, 0.f}, acc1 = {0.f, 0.f, 0.f, 0.f};
        for (int mc = 0; mc < NN; mc += 32) {
            float d[8];
#pragma unroll
            for (int j = 0; j < 8; ++j) {
                float4 pm = *reinterpret_cast<const float4*>(&poss[(mc + mko + j) * 4]);
                float arg = fmaf(sx, pm.x, fmaf(sy, pm.y, fmaf(sz, pm.z, base + pm.w)));
                d[j] = exp2f(arg);
            }
            union { s16x8 v; unsigned u[4]; } af;
#pragma unroll
            for (int j = 0; j < 4; ++j) af.u[j] = cvt_pk_bf16(d[2 * j], d[2 * j + 1]);
            s16x8 bb0 = *reinterpret_cast<const s16x8*>(&xT[XTI(la, mc + mko)]);
            s16x8 bb1 = *reinterpret_cast<const s16x8*>(&xT[XTI(la + 16, mc + mko)]);
            acc0 = __builtin_amdgcn_mfma_f32_16x16x32_bf16(af.v, bb0, acc0, 0, 0, 0);
            acc1 = __builtin_amdgcn_mfma_f32_16x16x32_bf16(af.v, bb1, acc1, 0, 0, 0);
        }
        const int i = la;
#pragma unroll
        for (int r = 0; r < 4; ++r) {
            int n = nb + w * 16 + (lane >> 4) * 4 + r;
            float v0 = acc0[r], v1 = acc1[r];
            if (i < 3) {
                const float* p = &poss[n * 4];
                v0 -= (i == 0) ? p[0] : (i == 1) ? p[1] : p[2];
            }
            ushort* vp = Vb + (((size_t)(b * NN + n)) * NHEAD + h) * NI;
            vp[i] = f2bf(v0);
            vp[i + 16] = f2bf(v1);
        }
    }
}

// ---------------------------------------------------------------------------
// Dispatch 2: gemm1. A bf16 (V), gload_lds staging, BM=128, fused stats.
// C written as bf16 RAW (pre-BN); stats from fp32 accs.
// ---------------------------------------------------------------------------
__global__ __launch_bounds__(256) void k_gemm1(const ushort* __restrict__ A,
                                               const ushort* __restrict__ W,
                                               const float* __restrict__ bias,
                                               ushort* __restrict__ Cb,
                                               float* __restrict__ sums,
                                               float* __restrict__ sumsq) {
    constexpr int K = 256, NC = 512, KS = K / 32;
    __shared__ ushort As[2][4096];
    __shared__ ushort Bs[2][2048];
    __shared__ float red[2][64];
    const int t = threadIdx.x;
    const int lane = t & 63;
    const int w = t >> 6;
    const int m0 = blockIdx.y * 128;
    const int n0 = blockIdx.x * 64;
    const int la = lane & 15;
    const int lk = (lane >> 4) * 8;
    const int lks = lk ^ ((la & 3) << 3);
    const int srow = t >> 2;
    const int scol = ((t & 3) ^ (srow & 3)) * 8;

    if (t < 64) { red[0][t] = 0.f; red[1][t] = 0.f; }

    f32x4 acc[2][4];
#pragma unroll
    for (int fm = 0; fm < 2; ++fm)
#pragma unroll
        for (int fn = 0; fn < 4; ++fn) acc[fm][fn] = (f32x4){0.f, 0.f, 0.f, 0.f};

    auto STAGE = [&](int buf, int k0) {
        GLOAD_LDS16(A + (size_t)(m0 + srow) * K + k0 + scol, &As[buf][t * 8]);
        GLOAD_LDS16(A + (size_t)(m0 + 64 + srow) * K + k0 + scol, &As[buf][2048 + t * 8]);
        GLOAD_LDS16(W + (size_t)(n0 + srow) * K + k0 + scol, &Bs[buf][t * 8]);
    };

    STAGE(0, 0);
    __syncthreads();
    int cur = 0;
    for (int ks = 0; ks < KS; ++ks) {
        if (ks + 1 < KS) STAGE(cur ^ 1, (ks + 1) * 32);
        s16x8 b0 = *reinterpret_cast<const s16x8*>(&Bs[cur][(0 + la) * 32 + lks]);
        s16x8 b1 = *reinterpret_cast<const s16x8*>(&Bs[cur][(16 + la) * 32 + lks]);
        s16x8 b2 = *reinterpret_cast<const s16x8*>(&Bs[cur][(32 + la) * 32 + lks]);
        s16x8 b3 = *reinterpret_cast<const s16x8*>(&Bs[cur][(48 + la) * 32 + lks]);
#pragma unroll
        for (int fm = 0; fm < 2; ++fm) {
            s16x8 a = *reinterpret_cast<const s16x8*>(&As[cur][(w * 32 + fm * 16 + la) * 32 + lks]);
            acc[fm][0] = __builtin_amdgcn_mfma_f32_16x16x32_bf16(a, b0, acc[fm][0], 0, 0, 0);
            acc[fm][1] = __builtin_amdgcn_mfma_f32_16x16x32_bf16(a, b1, acc[fm][1], 0, 0, 0);
            acc[fm][2] = __builtin_amdgcn_mfma_f32_16x16x32_bf16(a, b2, acc[fm][2], 0, 0, 0);
            acc[fm][3] = __builtin_amdgcn_mfma_f32_16x16x32_bf16(a, b3, acc[fm][3], 0, 0, 0);
        }
        __syncthreads();
        cur ^= 1;
    }

    float bv[4], s[4] = {}, q[4] = {};
#pragma unroll
    for (int fn = 0; fn < 4; ++fn) bv[fn] = bias[n0 + fn * 16 + la];
#pragma unroll
    for (int fm = 0; fm < 2; ++fm)
#pragma unroll
        for (int fn = 0; fn < 4; ++fn)
#pragma unroll
            for (int r = 0; r < 4; ++r) {
                int row = m0 + w * 32 + fm * 16 + (lane >> 4) * 4 + r;
                float v = acc[fm][fn][r] + bv[fn];
                Cb[(size_t)row * NC + n0 + fn * 16 + la] = f2bf(v);
                s[fn] += v; q[fn] += v * v;
            }
#pragma unroll
    for (int fn = 0; fn < 4; ++fn) {
        s[fn] += __shfl_xor(s[fn], 16); s[fn] += __shfl_xor(s[fn], 32);
        q[fn] += __shfl_xor(q[fn], 16); q[fn] += __shfl_xor(q[fn], 32);
    }
    if (lane < 16) {
#pragma unroll
        for (int fn = 0; fn < 4; ++fn) {
            atomicAdd(&red[0][fn * 16 + lane], s[fn]);
            atomicAdd(&red[1][fn * 16 + lane], q[fn]);
        }
    }
    __syncthreads();
    if (t < 64) {
        atomicAdd(&sums[n0 + t], red[0][t]);
        atomicAdd(&sumsq[n0 + t], red[1][t]);
    }
}

// ---------------------------------------------------------------------------
// Dispatch 3: gemm2. A = bf16 RAW prev-layer output (gload_lds staged);
// BN affine + leaky applied IN-REGISTER after ds_read, before MFMA.
// C written as bf16 RAW + fused stats.
// ---------------------------------------------------------------------------
template <int K, int NC>
__global__ __launch_bounds__(256) void k_gemm_bn(const ushort* __restrict__ Araw,
                                                 const ushort* __restrict__ W,
                                                 const float* __restrict__ bias,
                                                 const float* __restrict__ psum,
                                                 const float* __restrict__ psumsq,
                                                 const float* __restrict__ pg,
                                                 const float* __restrict__ pbt,
                                                 ushort* __restrict__ Cb,
                                                 float* __restrict__ sums,
                                                 float* __restrict__ sumsq) {
    constexpr int KS = K / 32;
    __shared__ ushort As[2][4096];
    __shared__ ushort Bs[2][2048];
    __shared__ float ca[K], cd[K];
    __shared__ float red[2][64];
    const int t = threadIdx.x;
    const int lane = t & 63;
    const int w = t >> 6;
    const int m0 = blockIdx.y * 128;
    const int n0 = blockIdx.x * 64;
    const int la = lane & 15;
    const int lk = (lane >> 4) * 8;
    const int lks = lk ^ ((la & 3) << 3);
    const int srow = t >> 2;
    const int scol = ((t & 3) ^ (srow & 3)) * 8;
    const float invn = 1.f / (float)ROWS;

    for (int c = t; c < K; c += 256) {
        float m = psum[c] * invn;
        float var = psumsq[c] * invn - m * m;
        float a = pg[c] * rsqrtf(var + EPSV);
        ca[c] = a;
        cd[c] = pbt[c] - m * a;
    }
    if (t < 64) { red[0][t] = 0.f; red[1][t] = 0.f; }

    auto STAGE = [&](int buf, int k0) {
        GLOAD_LDS16(Araw + (size_t)(m0 + srow) * K + k0 + scol, &As[buf][t * 8]);
        GLOAD_LDS16(Araw + (size_t)(m0 + 64 + srow) * K + k0 + scol, &As[buf][2048 + t * 8]);
        GLOAD_LDS16(W + (size_t)(n0 + srow) * K + k0 + scol, &Bs[buf][t * 8]);
    };

    f32x4 acc[2][4];
#pragma unroll
    for (int fm = 0; fm < 2; ++fm)
#pragma unroll
        for (int fn = 0; fn < 4; ++fn) acc[fm][fn] = (f32x4){0.f, 0.f, 0.f, 0.f};

    STAGE(0, 0);
    __syncthreads();           // covers ca/cd + staged data
    int cur = 0;
    for (int ks = 0; ks < KS; ++ks) {
        const int k0 = ks * 32;
        if (ks + 1 < KS) STAGE(cur ^ 1, (ks + 1) * 32);
        s16x8 b0 = *reinterpret_cast<const s16x8*>(&Bs[cur][(0 + la) * 32 + lks]);
        s16x8 b1 = *reinterpret_cast<const s16x8*>(&Bs[cur][(16 + la) * 32 + lks]);
        s16x8 b2 = *reinterpret_cast<const s16x8*>(&Bs[cur][(32 + la) * 32 + lks]);
        s16x8 b3 = *reinterpret_cast<const s16x8*>(&Bs[cur][(48 + la) * 32 + lks]);
        // BN coefs for this k-slice (broadcast reads within 16-lane groups)
        float4 ka0 = *reinterpret_cast<const float4*>(&ca[k0 + lk]);
        float4 ka1 = *reinterpret_cast<const float4*>(&ca[k0 + lk + 4]);
        float4 kd0 = *reinterpret_cast<const float4*>(&cd[k0 + lk]);
        float4 kd1 = *reinterpret_cast<const float4*>(&cd[k0 + lk + 4]);
        float kaf[8] = {ka0.x, ka0.y, ka0.z, ka0.w, ka1.x, ka1.y, ka1.z, ka1.w};
        float kdf[8] = {kd0.x, kd0.y, kd0.z, kd0.w, kd1.x, kd1.y, kd1.z, kd1.w};
#pragma unroll
        for (int fm = 0; fm < 2; ++fm) {
            union { s16x8 v; ushort us[8]; } araw;
            araw.v = *reinterpret_cast<const s16x8*>(&As[cur][(w * 32 + fm * 16 + la) * 32 + lks]);
            float y[8];
#pragma unroll
            for (int e = 0; e < 8; ++e) {
                float f = bf2f(araw.us[e]);
                float z = fmaf(kaf[e], f, kdf[e]);
                y[e] = fmaxf(z, 0.f) + SLOPE * fminf(z, 0.f);
            }
            union { s16x8 v; unsigned u[4]; } af;
#pragma unroll
            for (int p = 0; p < 4; ++p) af.u[p] = cvt_pk_bf16(y[2 * p], y[2 * p + 1]);
            acc[fm][0] = __builtin_amdgcn_mfma_f32_16x16x32_bf16(af.v, b0, acc[fm][0], 0, 0, 0);
            acc[fm][1] = __builtin_amdgcn_mfma_f32_16x16x32_bf16(af.v, b1, acc[fm][1], 0, 0, 0);
            acc[fm][2] = __builtin_amdgcn_mfma_f32_16x16x32_bf16(af.v, b2, acc[fm][2], 0, 0, 0);
            acc[fm][3] = __builtin_amdgcn_mfma_f32_16x16x32_bf16(af.v, b3, acc[fm][3], 0, 0, 0);
        }
        __syncthreads();
        cur ^= 1;
    }

    float bv[4], s[4] = {}, q[4] = {};
#pragma unroll
    for (int fn = 0; fn < 4; ++fn) bv[fn] = bias[n0 + fn * 16 + la];
#pragma unroll
    for (int fm = 0; fm < 2; ++fm)
#pragma unroll
        for (int fn = 0; fn < 4; ++fn)
#pragma unroll
            for (int r = 0; r < 4; ++r) {
                int row = m0 + w * 32 + fm * 16 + (lane >> 4) * 4 + r;
                float v = acc[fm][fn][r] + bv[fn];
                Cb[(size_t)row * NC + n0 + fn * 16 + la] = f2bf(v);
                s[fn] += v; q[fn] += v * v;
            }
#pragma unroll
    for (int fn = 0; fn < 4; ++fn) {
        s[fn] += __shfl_xor(s[fn], 16); s[fn] += __shfl_xor(s[fn], 32);
        q[fn] += __shfl_xor(q[fn], 16); q[fn] += __shfl_xor(q[fn], 32);
    }
    if (lane < 16) {
#pragma unroll
        for (int fn = 0; fn < 4; ++fn) {
            atomicAdd(&red[0][fn * 16 + lane], s[fn]);
            atomicAdd(&red[1][fn * 16 + lane], q[fn]);
        }
    }
    __syncthreads();
    if (t < 64) {
        atomicAdd(&sums[n0 + t], red[0][t]);
        atomicAdd(&sumsq[n0 + t], red[1][t]);
    }
}

// ---------------------------------------------------------------------------
// Dispatch 4: gemm3. A = bf16 RAW Y2 (16x32 tile staged by wave 0),
// BN2+leaky in-register post-ds_read; C fp32 + stats.
// ---------------------------------------------------------------------------
__global__ __launch_bounds__(256) void k_gemm3_bn(const ushort* __restrict__ Araw,
                                                  const ushort* __restrict__ W,
                                                  const float* __restrict__ bias,
                                                  const float* __restrict__ psum,
                                                  const float* __restrict__ psumsq,
                                                  const float* __restrict__ pg,
                                                  const float* __restrict__ pbt,
                                                  float* __restrict__ C,
                                                  float* __restrict__ sums,
                                                  float* __restrict__ sumsq) {
    constexpr int K = 512, KS = 16;
    __shared__ ushort As[2][512];
    __shared__ ushort Bs[2][2048];
    __shared__ float ca[K], cd[K];
    const int t = threadIdx.x;
    const int lane = t & 63;
    const int w = t >> 6;
    const int m0 = blockIdx.x * 16;
    const int la = lane & 15;
    const int lk = (lane >> 4) * 8;
    const int lks = lk ^ ((la & 3) << 3);
    const int srow = t >> 2;
    const int scol = ((t & 3) ^ (srow & 3)) * 8;
    const int srow3 = lane >> 2;
    const int scol3 = ((lane & 3) ^ (srow3 & 3)) * 8;
    const float invn = 1.f / (float)ROWS;

    for (int c = t; c < K; c += 256) {
        float m = psum[c] * invn;
        float var = psumsq[c] * invn - m * m;
        float a = pg[c] * rsqrtf(var + EPSV);
        ca[c] = a;
        cd[c] = pbt[c] - m * a;
    }

    auto STAGE = [&](int buf, int k0) {
        if (w == 0)
            GLOAD_LDS16(Araw + (size_t)(m0 + srow3) * K + k0 + scol3, &As[buf][lane * 8]);
        GLOAD_LDS16(W + (size_t)srow * K + k0 + scol, &Bs[buf][t * 8]);
    };

    f32x4 acc = {0.f, 0.f, 0.f, 0.f};
    STAGE(0, 0);
    __syncthreads();
    int cur = 0;
    for (int ks = 0; ks < KS; ++ks) {
        const int k0 = ks * 32;
        if (ks + 1 < KS) STAGE(cur ^ 1, (ks + 1) * 32);
        float4 ka0 = *reinterpret_cast<const float4*>(&ca[k0 + lk]);
        float4 ka1 = *reinterpret_cast<const float4*>(&ca[k0 + lk + 4]);
        float4 kd0 = *reinterpret_cast<const float4*>(&cd[k0 + lk]);
        float4 kd1 = *reinterpret_cast<const float4*>(&cd[k0 + lk + 4]);
        float kaf[8] = {ka0.x, ka0.y, ka0.z, ka0.w, ka1.x, ka1.y, ka1.z, ka1.w};
        float kdf[8] = {kd0.x, kd0.y, kd0.z, kd0.w, kd1.x, kd1.y, kd1.z, kd1.w};
        union { s16x8 v; ushort us[8]; } araw;
        araw.v = *reinterpret_cast<const s16x8*>(&As[cur][la * 32 + lks]);
        float y[8];
#pragma unroll
        for (int e = 0; e < 8; ++e) {
            float f = bf2f(araw.us[e]);
            float z = fmaf(kaf[e], f, kdf[e]);
            y[e] = fmaxf(z, 0.f) + SLOPE * fminf(z, 0.f);
        }
        union { s16x8 v; unsigned u[4]; } af;
#pragma unroll
        for (int p = 0; p < 4; ++p) af.u[p] = cvt_pk_bf16(y[2 * p], y[2 * p + 1]);
        s16x8 bb = *reinterpret_cast<const s16x8*>(&Bs[cur][(w * 16 + la) * 32 + lks]);
        acc = __builtin_amdgcn_mfma_f32_16x16x32_bf16(af.v, bb, acc, 0, 0, 0);
        __syncthreads();
        cur ^= 1;
    }

    float bv = bias[w * 16 + la];
    float s = 0.f, q = 0.f;
#pragma unroll
    for (int r = 0; r < 4; ++r) {
        int row = m0 + (lane >> 4) * 4 + r;
        float v = acc[r] + bv;
        C[(size_t)row * NO + w * 16 + la] = v;
        s += v; q += v * v;
    }
    s += __shfl_xor(s, 16); s += __shfl_xor(s, 32);
    q += __shfl_xor(q, 16); q += __shfl_xor(q, 32);
    if (lane < 16) {
        atomicAdd(&sums[w * 16 + la], s);
        atomicAdd(&sumsq[w * 16 + la], q);
    }
}

// ---------------------------------------------------------------------------
// Dispatch 5: final BN -> out.
// ---------------------------------------------------------------------------
__global__ __launch_bounds__(256) void k_bn3(const float* __restrict__ Yin,
                                             float* __restrict__ Yout,
                                             const float* __restrict__ sums,
                                             const float* __restrict__ sumsq,
                                             const float* __restrict__ g,
                                             const float* __restrict__ bt) {
    const float invn = 1.f / (float)ROWS;
    int e = blockIdx.x * 256 + threadIdx.x;
    int c0 = (e * 4) & (NO - 1);
    float4 v = reinterpret_cast<const float4*>(Yin)[e];
    float vv[4] = {v.x, v.y, v.z, v.w};
    float oo[4];
#pragma unroll
    for (int j = 0; j < 4; ++j) {
        int c = c0 + j;
        float m = sums[c] * invn;
        float var = sumsq[c] * invn - m * m;
        float rs = rsqrtf(var + EPSV);
        oo[j] = (vv[j] - m) * rs * g[c] + bt[c];
    }
    reinterpret_cast<float4*>(Yout)[e] = make_float4(oo[0], oo[1], oo[2], oo[3]);
}

extern "C" void kernel_launch(void* const* d_in, const int* in_sizes, int n_in,
                              void* d_out, int out_size, void* d_ws, size_t ws_size,
                              hipStream_t stream) {
    const float* x   = (const float*)d_in[0];
    const float* Q   = (const float*)d_in[1];
    const float* W1  = (const float*)d_in[2];
    const float* b1  = (const float*)d_in[3];
    const float* g1  = (const float*)d_in[4];
    const float* bt1 = (const float*)d_in[5];
    const float* W2  = (const float*)d_in[6];
    const float* b2  = (const float*)d_in[7];
    const float* g2  = (const float*)d_in[8];
    const float* bt2 = (const float*)d_in[9];
    const float* W3  = (const float*)d_in[10];
    const float* b3  = (const float*)d_in[11];
    const float* g3  = (const float*)d_in[12];
    const float* bt3 = (const float*)d_in[13];
    float* out = (float*)d_out;

    char* wsb = (char*)d_ws;
    ushort* Vb   = (ushort*)wsb;                     // [0,4M)   bf16 8192x256
    ushort* Y1rb = (ushort*)(wsb + (4u << 20));      // [4,12M)  bf16 raw 8192x512
    ushort* Y2rb = (ushort*)(wsb + (12u << 20));     // [12,20M) bf16 raw 8192x512
    float*  Yr3  = (float*)(wsb + (20u << 20));      // [20,22M) fp32 8192x64
    ushort* W1b  = (ushort*)(wsb + (24u << 20));
    ushort* W2b  = W1b + 512 * 256;
    ushort* W3b  = W2b + 512 * 512;
    float*  st   = (float*)(W3b + 64 * 512);
    float* s1 = st;        float* q1 = s1 + 512;
    float* s2 = q1 + 512;  float* q2 = s2 + 512;
    float* s3 = q2 + 512;  float* q3 = s3 + 64;

    k_getv_wconv<<<576, 256, 0, stream>>>(x, Q, Vb, W1, W2, W3, W1b, W2b, W3b, st);

    k_gemm1<<<dim3(8, 64), 256, 0, stream>>>(Vb, W1b, b1, Y1rb, s1, q1);

    k_gemm_bn<512, 512><<<dim3(8, 64), 256, 0, stream>>>(
        Y1rb, W2b, b2, s1, q1, g1, bt1, Y2rb, s2, q2);

    k_gemm3_bn<<<512, 256, 0, stream>>>(
        Y2rb, W3b, b3, s2, q2, g2, bt2, Yr3, s3, q3);

    k_bn3<<<512, 256, 0, stream>>>(Yr3, out, s3, q3, g3, bt3);
}